// Round 1
// baseline (4313.230 us; speedup 1.0000x reference)
//
#include <hip/hip_runtime.h>
#include <hip/hip_bf16.h>
#include <math.h>

#define G_ 32000
#define E_ 256
#define K_ 8
#define D_ 6
#define B_ 4
#define L_ 512
#define M_ 64
#define KN_ 4
#define STEP_ 0.05f

// ---------------- reduction helpers ----------------
__device__ __forceinline__ float wsum(float v) {
#pragma unroll
  for (int o = 32; o > 0; o >>= 1) v += __shfl_xor(v, o, 64);
  return v;
}
__device__ __forceinline__ float wmax(float v) {
#pragma unroll
  for (int o = 32; o > 0; o >>= 1) v = fmaxf(v, __shfl_xor(v, o, 64));
  return v;
}
__device__ __forceinline__ float block_sum(float v, float* sm) {
  v = wsum(v);
  int wid = threadIdx.x >> 6, lane = threadIdx.x & 63;
  if (lane == 0) sm[wid] = v;
  __syncthreads();
  float r = sm[0] + sm[1] + sm[2] + sm[3];
  __syncthreads();
  return r;
}
__device__ __forceinline__ float block_max(float v, float* sm) {
  v = wmax(v);
  int wid = threadIdx.x >> 6, lane = threadIdx.x & 63;
  if (lane == 0) sm[wid] = v;
  __syncthreads();
  float r = fmaxf(fmaxf(sm[0], sm[1]), fmaxf(sm[2], sm[3]));
  __syncthreads();
  return r;
}

// ---------------- tiled fp32 GEMM ----------------
// C[M,N] = op(A[M,K] @ B) with optional transB, relu, accumulate, bias, scale.
// Batched via gridDim.z with two batch strides (z -> b1 = z/batch2, b2 = z%batch2).
template <int BM, int BN, int BK, int TM, int TN, bool TRB, bool RELU, bool ACC,
          bool BIAS, bool SCL>
__global__ __launch_bounds__(256) void gemm_k(
    const float* __restrict__ Ag, const float* __restrict__ Bg,
    float* __restrict__ Cg, const float* __restrict__ bias, float scale, int M,
    int N, int Kd, int lda, int ldb, int ldc, int batch2, long sA1, long sA2,
    long sB1, long sB2, long sC1, long sC2) {
  int bz = blockIdx.z;
  int b1 = bz / batch2, b2 = bz - b1 * batch2;
  const float* A = Ag + b1 * sA1 + b2 * sA2;
  const float* Bp = Bg + b1 * sB1 + b2 * sB2;
  float* C = Cg + b1 * sC1 + b2 * sC2;
  int m0 = blockIdx.y * BM, n0 = blockIdx.x * BN;
  __shared__ float As[BK][BM + 4];
  __shared__ float Bs[BK][BN + 4];
  int t = threadIdx.x;
  constexpr int NTX = BN / TN;
  int tx = t % NTX, ty = t / NTX;
  float acc[TM][TN];
#pragma unroll
  for (int i = 0; i < TM; i++)
#pragma unroll
    for (int j = 0; j < TN; j++) acc[i][j] = 0.f;

  for (int k0 = 0; k0 < Kd; k0 += BK) {
    __syncthreads();
    {  // A tile: BM x BK, stored transposed As[k][m]
      constexpr int NF4 = (BM * BK) / 1024;
#pragma unroll
      for (int c = 0; c < NF4; c++) {
        int i = t + c * 256;
        int r = i / (BK / 4);
        int kc = (i % (BK / 4)) * 4;
        float4 v = *(const float4*)(A + (long)(m0 + r) * lda + k0 + kc);
        As[kc + 0][r] = v.x;
        As[kc + 1][r] = v.y;
        As[kc + 2][r] = v.z;
        As[kc + 3][r] = v.w;
      }
    }
    if (!TRB) {  // B is (K,N) row-major
      constexpr int NF4 = (BK * BN) / 1024;
#pragma unroll
      for (int c = 0; c < NF4; c++) {
        int i = t + c * 256;
        int r = i / (BN / 4);
        int nc = (i % (BN / 4)) * 4;
        *(float4*)(&Bs[r][nc]) =
            *(const float4*)(Bp + (long)(k0 + r) * ldb + n0 + nc);
      }
    } else {  // B is (N,K) row-major (transposed use)
      constexpr int NF4 = (BN * BK) / 1024;
#pragma unroll
      for (int c = 0; c < NF4; c++) {
        int i = t + c * 256;
        int n = i / (BK / 4);
        int kc = (i % (BK / 4)) * 4;
        float4 v = *(const float4*)(Bp + (long)(n0 + n) * ldb + k0 + kc);
        Bs[kc + 0][n] = v.x;
        Bs[kc + 1][n] = v.y;
        Bs[kc + 2][n] = v.z;
        Bs[kc + 3][n] = v.w;
      }
    }
    __syncthreads();
#pragma unroll
    for (int kk = 0; kk < BK; kk++) {
      float a[TM], b[TN];
#pragma unroll
      for (int i4 = 0; i4 < TM / 4; i4++)
        *(float4*)(&a[i4 * 4]) = *(const float4*)(&As[kk][ty * TM + i4 * 4]);
#pragma unroll
      for (int j4 = 0; j4 < TN / 4; j4++)
        *(float4*)(&b[j4 * 4]) = *(const float4*)(&Bs[kk][tx * TN + j4 * 4]);
#pragma unroll
      for (int i = 0; i < TM; i++)
#pragma unroll
        for (int j = 0; j < TN; j++) acc[i][j] = fmaf(a[i], b[j], acc[i][j]);
    }
  }
#pragma unroll
  for (int i = 0; i < TM; i++) {
    long row = m0 + ty * TM + i;
    float* cp = C + row * (long)ldc + n0 + tx * TN;
#pragma unroll
    for (int j = 0; j < TN; j++) {
      float v = acc[i][j];
      if (SCL) v *= scale;
      if (BIAS) v += bias[n0 + tx * TN + j];
      if (RELU) v = fmaxf(v, 0.f);
      if (ACC) v += cp[j];
      cp[j] = v;
    }
  }
}

// ---------------- small fused kernels ----------------
__global__ __launch_bounds__(256) void embed_init_k(
    const int* __restrict__ masked, const float* __restrict__ embed,
    const float* __restrict__ pos, float* __restrict__ xsa) {
  int bl = blockIdx.x;
  int l = bl % L_;
  int t = threadIdx.x;
  __shared__ float sm[4];
  int tok = masked[bl];
  float v = embed[(long)tok * E_ + t] + pos[(long)l * E_ + t];
  float s1 = block_sum(v, sm);
  float s2 = block_sum(v * v, sm);
  float mean = s1 * (1.0f / E_);
  float var = (s2 - s1 * mean) * (1.0f / (E_ - 1));
  xsa[(long)bl * E_ + t] = v / (1.0f + sqrtf(fmaxf(var, 0.f)));
}

__global__ __launch_bounds__(256) void roll_copy_k(const float* __restrict__ src,
                                                   float* __restrict__ dst,
                                                   int shift) {
  int bl = blockIdx.x;
  int b = bl / L_, l = bl % L_;
  int t = threadIdx.x;
  int sl = (l - shift + L_) % L_;
  dst[(long)bl * E_ + t] = src[((long)b * L_ + sl) * E_ + t];
}

__global__ __launch_bounds__(256) void softmax_rows_k(float* __restrict__ x) {
  long row = blockIdx.x;
  float* p = x + row * (long)L_;
  int t = threadIdx.x;
  __shared__ float sm[4];
  float v0 = p[t], v1 = p[t + 256];
  float mx = block_max(fmaxf(v0, v1), sm);
  float e0 = __expf(v0 - mx), e1 = __expf(v1 - mx);
  float s = block_sum(e0 + e1, sm);
  float inv = 1.0f / s;
  p[t] = e0 * inv;
  p[t + 256] = e1 * inv;
}

__global__ __launch_bounds__(256) void update_norm_k(
    float* __restrict__ xsa, const float* __restrict__ xsad) {
  long r = blockIdx.x;
  int t = threadIdx.x;
  __shared__ float sm[4];
  float vd = xsad[r * E_ + t];
  float s1 = block_sum(vd, sm);
  float s2 = block_sum(vd * vd, sm);
  float mean = s1 * (1.0f / E_);
  float var = (s2 - s1 * mean) * (1.0f / (E_ - 1));
  float vdn = vd / (1.0f + sqrtf(fmaxf(var, 0.f)));
  float u = xsa[r * E_ + t] + STEP_ * vdn;
  s1 = block_sum(u, sm);
  s2 = block_sum(u * u, sm);
  mean = s1 * (1.0f / E_);
  var = (s2 - s1 * mean) * (1.0f / (E_ - 1));
  xsa[r * E_ + t] = u / (1.0f + sqrtf(fmaxf(var, 0.f)));
}

__global__ __launch_bounds__(256) void gather_k(const float* __restrict__ xsa,
                                                const int* __restrict__ mask,
                                                float* __restrict__ lptok) {
  int bm = blockIdx.x;
  int b = bm >> 6;  // M_=64
  int t = threadIdx.x;
  int p = mask[bm];
  lptok[(long)bm * E_ + t] = xsa[((long)b * L_ + p) * E_ + t];
}

// Fused logits + per-row online logsumexp over the vocab.
// grid = (1024/RN)*NSPLIT blocks; each block handles RN rows, one g-split.
#define RN_ 16
#define NSPLIT_ 4
__global__ __launch_bounds__(256) void lse_embed_k(
    const float* __restrict__ tmat, const float* __restrict__ embed,
    float* __restrict__ mpart, float* __restrict__ spart) {
  const int GS = G_ / NSPLIT_;
  int blk = blockIdx.x;
  int split = blk % NSPLIT_, rb = blk / NSPLIT_;
  __shared__ float tl[RN_][E_];
  __shared__ float rm[RN_][256];
  __shared__ float rs[RN_][256];
  int t = threadIdx.x;
  for (int i = t; i < RN_ * E_; i += 256)
    tl[i >> 8][i & 255] = tmat[(long)rb * RN_ * E_ + i];
  __syncthreads();
  float m[RN_], s[RN_];
#pragma unroll
  for (int r = 0; r < RN_; r++) {
    m[r] = -INFINITY;
    s[r] = 0.f;
  }
  int gend = split * GS + GS;
  for (int g = split * GS + t; g < gend; g += 256) {
    const float4* er = (const float4*)(embed + (long)g * E_);
    float d[RN_];
#pragma unroll
    for (int r = 0; r < RN_; r++) d[r] = 0.f;
    for (int e4 = 0; e4 < E_ / 4; e4++) {
      float4 ev = er[e4];
#pragma unroll
      for (int r = 0; r < RN_; r++) {
        float4 tv = *(const float4*)(&tl[r][e4 * 4]);
        d[r] += ev.x * tv.x + ev.y * tv.y + ev.z * tv.z + ev.w * tv.w;
      }
    }
#pragma unroll
    for (int r = 0; r < RN_; r++) {
      float mn = fmaxf(m[r], d[r]);
      s[r] = s[r] * __expf(m[r] - mn) + __expf(d[r] - mn);
      m[r] = mn;
    }
  }
#pragma unroll
  for (int r = 0; r < RN_; r++) {
    rm[r][t] = m[r];
    rs[r][t] = s[r];
  }
  __syncthreads();
  if (t < RN_) {
    float M = -INFINITY, S = 0.f;
    for (int i = 0; i < 256; i++) {
      float m2 = rm[t][i], s2 = rs[t][i];
      float MM = fmaxf(M, m2);
      S = S * __expf(M - MM) + s2 * __expf(m2 - MM);
      M = MM;
    }
    long row = (long)rb * RN_ + t;
    mpart[row * NSPLIT_ + split] = M;
    spart[row * NSPLIT_ + split] = S;
  }
}

__global__ __launch_bounds__(256) void cent_k(
    const float* __restrict__ tmat, const float* __restrict__ embed,
    const int* __restrict__ mask, const int* __restrict__ unmasked,
    const float* __restrict__ mpart, const float* __restrict__ spart,
    float* __restrict__ cent) {
  int bm = blockIdx.x;
  int b = bm >> 6, m = bm & 63;
  int t = threadIdx.x;
  __shared__ float sm[4];
  __shared__ float tlv[KN_];
  int pos = mask[bm];
  int tgt = unmasked[b * L_ + pos];
  float ev = embed[(long)tgt * E_ + t];
  for (int kn = 0; kn < KN_; kn++) {
    long grow = (long)b * (M_ * KN_) + m * KN_ + kn;
    float dot = block_sum(tmat[grow * E_ + t] * ev, sm);
    if (t == 0) {
      float M = -INFINITY, S = 0.f;
      for (int i = 0; i < NSPLIT_; i++) {
        float m2 = mpart[grow * NSPLIT_ + i], s2 = spart[grow * NSPLIT_ + i];
        float MM = fmaxf(M, m2);
        S = S * __expf(M - MM) + s2 * __expf(m2 - MM);
        M = MM;
      }
      float lse = M + __logf(S);
      tlv[kn] = dot - lse;
    }
  }
  __syncthreads();
  if (t == 0) {
    float mx = fmaxf(fmaxf(tlv[0], tlv[1]), fmaxf(tlv[2], tlv[3]));
    float s = __expf(tlv[0] - mx) + __expf(tlv[1] - mx) + __expf(tlv[2] - mx) +
              __expf(tlv[3] - mx);
    cent[bm] = __logf(s) + mx - 1.3862943611198906f;  // - log(KN)
  }
}

__global__ __launch_bounds__(256) void loss_k(const float* __restrict__ cent,
                                              const float* __restrict__ summer,
                                              float* __restrict__ out) {
  int t = threadIdx.x;
  int b = t >> 6, m = t & 63;
  float c = cent[b * 64 + m], su = summer[b * 64 + m];
  float num = wsum(c * su);
  float den = wsum(su);
  if (m == 0) out[b] = -num / fmaxf(den, 1.0f);
}

// ---------------- launcher ----------------
extern "C" void kernel_launch(void* const* d_in, const int* in_sizes, int n_in,
                              void* d_out, int out_size, void* d_ws,
                              size_t ws_size, hipStream_t stream) {
  (void)in_sizes; (void)n_in; (void)out_size; (void)ws_size;
  const int* masked = (const int*)d_in[0];
  const int* unmasked = (const int*)d_in[1];
  const int* mask = (const int*)d_in[2];
  const float* summer = (const float*)d_in[3];
  const float* embed = (const float*)d_in[4];
  const float* pos = (const float*)d_in[5];
  const float* Wt = (const float*)d_in[6];
  const float* Wc = (const float*)d_in[7];
  const float* Wq = (const float*)d_in[8];
  const float* Wd = (const float*)d_in[9];
  const float* Wo = (const float*)d_in[10];
  const float* Wkc = (const float*)d_in[11];
  const float* bkc = (const float*)d_in[12];
  const float* Wem = (const float*)d_in[13];
  float* out = (float*)d_out;

  float* w = (float*)d_ws;
  float* xsa = w;    w += (long)B_ * L_ * E_;
  float* xsad = w;   w += (long)B_ * L_ * E_;
  float* rolled = w; w += (long)B_ * L_ * E_;
  float* tmp = w;    w += (long)B_ * L_ * E_;
  float* q = w;      w += (long)B_ * L_ * K_ * E_;  // also yik
  float* xid = w;    w += (long)B_ * L_ * K_ * E_;
  float* sc = w;     w += (long)B_ * K_ * L_ * L_;
  float* lptok = w;  w += (long)B_ * M_ * E_;
  float* xx1 = w;    w += (long)B_ * M_ * KN_ * E_;
  float* xx2 = w;    w += (long)B_ * M_ * KN_ * L_;
  float* xx3 = w;    w += (long)B_ * M_ * KN_ * E_;
  float* tmat = w;   w += (long)B_ * M_ * KN_ * E_;
  float* mpart = w;  w += 1024 * NSPLIT_;
  float* spart = w;  w += 1024 * NSPLIT_;
  float* cent = w;   w += B_ * M_;

  dim3 blk(256);
  embed_init_k<<<B_ * L_, blk, 0, stream>>>(masked, embed, pos, xsa);

  for (int d = 0; d < D_; d++) {
    const float* Wt_d = Wt + (long)d * E_ * E_;
    const float* Wc_d = Wc + (long)d * E_ * E_;
    const float* Wq_d = Wq + (long)d * K_ * E_ * E_;
    const float* Wd_d = Wd + (long)d * K_ * E_ * K_ * E_;
    const float* Wo_d = Wo + (long)d * K_ * E_ * E_;

    // local transition terms
    roll_copy_k<<<B_ * L_, blk, 0, stream>>>(xsa, rolled, 1);
    gemm_k<64, 64, 16, 4, 4, false, true, false, false, false>
        <<<dim3(E_ / 64, (B_ * L_) / 64, 1), blk, 0, stream>>>(
            rolled, Wt_d, tmp, nullptr, 1.f, B_ * L_, E_, E_, E_, E_, E_, 1, 0,
            0, 0, 0, 0, 0);
    gemm_k<64, 64, 16, 4, 4, false, false, false, false, false>
        <<<dim3(E_ / 64, (B_ * L_) / 64, 1), blk, 0, stream>>>(
            tmp, Wc_d, xsad, nullptr, 1.f, B_ * L_, E_, E_, E_, E_, E_, 1, 0, 0,
            0, 0, 0, 0);
    roll_copy_k<<<B_ * L_, blk, 0, stream>>>(xsa, rolled, -1);
    gemm_k<64, 64, 16, 4, 4, true, true, false, false, false>
        <<<dim3(E_ / 64, (B_ * L_) / 64, 1), blk, 0, stream>>>(
            rolled, Wc_d, tmp, nullptr, 1.f, B_ * L_, E_, E_, E_, E_, E_, 1, 0,
            0, 0, 0, 0, 0);
    gemm_k<64, 64, 16, 4, 4, true, false, true, false, false>
        <<<dim3(E_ / 64, (B_ * L_) / 64, 1), blk, 0, stream>>>(
            tmp, Wt_d, xsad, nullptr, 1.f, B_ * L_, E_, E_, E_, E_, E_, 1, 0, 0,
            0, 0, 0, 0);

    // q = xsa @ Wq^T
    gemm_k<128, 128, 16, 8, 8, true, false, false, false, false>
        <<<dim3((K_ * E_) / 128, (B_ * L_) / 128, 1), blk, 0, stream>>>(
            xsa, Wq_d, q, nullptr, 1.f, B_ * L_, K_ * E_, E_, E_, E_, K_ * E_,
            1, 0, 0, 0, 0, 0, 0);
    // scores[b,k] = q[b,:,k,:] @ xsa[b]^T * (1/16)
    gemm_k<128, 128, 16, 8, 8, true, false, false, false, true>
        <<<dim3(L_ / 128, L_ / 128, B_ * K_), blk, 0, stream>>>(
            q, xsa, sc, nullptr, 0.0625f, L_, L_, E_, K_ * E_, E_, L_, K_,
            (long)L_ * K_ * E_, 256, (long)L_ * E_, 0, (long)K_ * L_ * L_,
            (long)L_ * L_);
    softmax_rows_k<<<B_ * K_ * L_, blk, 0, stream>>>(sc);
    // yik[b,k] = P @ xsa[b]  (into q buffer, layout (B,L,K,E))
    gemm_k<128, 128, 16, 8, 8, false, false, false, false, false>
        <<<dim3(E_ / 128, L_ / 128, B_ * K_), blk, 0, stream>>>(
            sc, xsa, q, nullptr, 1.f, L_, E_, L_, L_, E_, K_ * E_, K_,
            (long)K_ * L_ * L_, (long)L_ * L_, (long)L_ * E_, 0,
            (long)L_ * K_ * E_, 256);
    // xid = relu(yik @ Wd^T)
    gemm_k<128, 128, 16, 8, 8, true, true, false, false, false>
        <<<dim3((K_ * E_) / 128, (B_ * L_) / 128, 1), blk, 0, stream>>>(
            q, Wd_d, xid, nullptr, 1.f, B_ * L_, K_ * E_, K_ * E_, K_ * E_,
            K_ * E_, K_ * E_, 1, 0, 0, 0, 0, 0, 0);
    // xsad += xid @ Wo
    gemm_k<64, 64, 16, 4, 4, false, false, true, false, false>
        <<<dim3(E_ / 64, (B_ * L_) / 64, 1), blk, 0, stream>>>(
            xid, Wo_d, xsad, nullptr, 1.f, B_ * L_, E_, K_ * E_, K_ * E_, E_,
            E_, 1, 0, 0, 0, 0, 0, 0);

    update_norm_k<<<B_ * L_, blk, 0, stream>>>(xsa, xsad);
  }

  // ---- loss head ----
  gather_k<<<B_ * M_, blk, 0, stream>>>(xsa, mask, lptok);
  gemm_k<64, 64, 16, 4, 4, true, false, false, true, false>
      <<<dim3((KN_ * E_) / 64, (B_ * M_) / 64, 1), blk, 0, stream>>>(
          lptok, Wkc, xx1, bkc, 1.f, B_ * M_, KN_ * E_, E_, E_, E_, KN_ * E_, 1,
          0, 0, 0, 0, 0, 0);
  gemm_k<64, 64, 16, 4, 4, true, false, false, false, false>
      <<<dim3(L_ / 64, (M_ * KN_) / 64, B_), blk, 0, stream>>>(
          xx1, xsa, xx2, nullptr, 1.f, M_ * KN_, L_, E_, E_, E_, L_, 1,
          (long)M_ * KN_ * E_, 0, (long)L_ * E_, 0, (long)M_ * KN_ * L_, 0);
  gemm_k<64, 64, 16, 4, 4, false, false, false, false, false>
      <<<dim3(E_ / 64, (M_ * KN_) / 64, B_), blk, 0, stream>>>(
          xx2, xsa, xx3, nullptr, 1.f, M_ * KN_, E_, L_, L_, E_, E_, 1,
          (long)M_ * KN_ * L_, 0, (long)L_ * E_, 0, (long)M_ * KN_ * E_, 0);
  gemm_k<64, 64, 16, 4, 4, false, false, false, false, false>
      <<<dim3(E_ / 64, (M_ * KN_) / 64, B_), blk, 0, stream>>>(
          xx3, Wem, tmat, nullptr, 1.f, M_ * KN_, E_, E_, E_, E_, E_, 1,
          (long)M_ * KN_ * E_, 0, 0, 0, (long)M_ * KN_ * E_, 0);
  lse_embed_k<<<((B_ * M_ * KN_) / RN_) * NSPLIT_, blk, 0, stream>>>(
      tmat, embed, mpart, spart);
  cent_k<<<B_ * M_, blk, 0, stream>>>(tmat, embed, mask, unmasked, mpart, spart,
                                      cent);
  loss_k<<<1, blk, 0, stream>>>(cent, summer, out);
}

// Round 2
// 1557.759 us; speedup vs baseline: 2.7689x; 2.7689x over previous
//
#include <hip/hip_runtime.h>
#include <math.h>

#define G_ 32000
#define E_ 256
#define K_ 8
#define D_ 6
#define B_ 4
#define L_ 512
#define M_ 64
#define KN_ 4
#define STEP_ 0.05f
#define BL_ (B_ * L_)   // 2048
#define KE_ (K_ * E_)   // 2048
#define NSPLIT_ 16

typedef __attribute__((ext_vector_type(8))) short short8;
typedef __attribute__((ext_vector_type(4))) float f32x4;
typedef __attribute__((ext_vector_type(4))) short short4v;

__device__ __forceinline__ short f2bf(float f) {
  unsigned u = __builtin_bit_cast(unsigned, f);
  unsigned r = (u + 0x7fffu + ((u >> 16) & 1u)) >> 16;
  return (short)r;
}

// ---------------- reduction helpers ----------------
__device__ __forceinline__ float wsum(float v) {
#pragma unroll
  for (int o = 32; o > 0; o >>= 1) v += __shfl_xor(v, o, 64);
  return v;
}
__device__ __forceinline__ float block_sum(float v, float* sm) {
  v = wsum(v);
  int wid = threadIdx.x >> 6, lane = threadIdx.x & 63;
  if (lane == 0) sm[wid] = v;
  __syncthreads();
  float r = sm[0] + sm[1] + sm[2] + sm[3];
  __syncthreads();
  return r;
}
__device__ __forceinline__ float wmax(float v) {
#pragma unroll
  for (int o = 32; o > 0; o >>= 1) v = fmaxf(v, __shfl_xor(v, o, 64));
  return v;
}
__device__ __forceinline__ float block_max(float v, float* sm) {
  v = wmax(v);
  int wid = threadIdx.x >> 6, lane = threadIdx.x & 63;
  if (lane == 0) sm[wid] = v;
  __syncthreads();
  float r = fmaxf(fmaxf(sm[0], sm[1]), fmaxf(sm[2], sm[3]));
  __syncthreads();
  return r;
}

// ---------------- bf16 MFMA GEMM ----------------
// C[M,N] = A[M,K] @ B^T where B is stored (N,K) row-major bf16. BK=64.
// 4 waves: 2x2 wave grid, each wave (BM/2)x(BN/2) via 16x16x32 MFMA frags.
template <int BM, int BN, bool RELU, bool ACC, bool SCL, bool OBF>
__global__ __launch_bounds__(256) void mgemm_k(
    const short* __restrict__ Ag, const short* __restrict__ Bg,
    void* __restrict__ Cg, float scale, int Kd, int lda, int ldb, int ldc,
    int batch2, long sA1, long sA2, long sB1, long sB2, long sC1, long sC2) {
  constexpr int PAD = 72;  // 64 + 8 (breaks bank-conflict power-of-2 stride)
  __shared__ short As[BM * PAD];
  __shared__ short Bs[BN * PAD];
  int bz = blockIdx.z;
  int b1 = bz / batch2, b2 = bz - b1 * batch2;
  const short* A = Ag + b1 * sA1 + b2 * sA2;
  const short* B = Bg + b1 * sB1 + b2 * sB2;
  int m0 = blockIdx.y * BM, n0 = blockIdx.x * BN;
  int t = threadIdx.x;
  int w = t >> 6, l = t & 63;
  int l16 = l & 15, hi8 = (l >> 4) * 8;
  constexpr int FRM = BM / 32, FRN = BN / 32;
  constexpr int WTM = BM / 2, WTN = BN / 2;
  int wr = w >> 1, wc = w & 1;
  f32x4 acc[FRM][FRN];
#pragma unroll
  for (int i = 0; i < FRM; i++)
#pragma unroll
    for (int j = 0; j < FRN; j++) acc[i][j] = {0.f, 0.f, 0.f, 0.f};

  for (int k0 = 0; k0 < Kd; k0 += 64) {
    __syncthreads();
#pragma unroll 2
    for (int i = t; i < BM * 8; i += 256) {
      int r = i >> 3, c = (i & 7) * 8;
      *(short8*)&As[r * PAD + c] =
          *(const short8*)(A + (long)(m0 + r) * lda + k0 + c);
    }
#pragma unroll 2
    for (int i = t; i < BN * 8; i += 256) {
      int r = i >> 3, c = (i & 7) * 8;
      *(short8*)&Bs[r * PAD + c] =
          *(const short8*)(B + (long)(n0 + r) * ldb + k0 + c);
    }
    __syncthreads();
#pragma unroll
    for (int ks = 0; ks < 2; ks++) {
      short8 af[FRM], bfr[FRN];
#pragma unroll
      for (int rf = 0; rf < FRM; rf++)
        af[rf] = *(const short8*)&As[(wr * WTM + rf * 16 + l16) * PAD +
                                     ks * 32 + hi8];
#pragma unroll
      for (int cf = 0; cf < FRN; cf++)
        bfr[cf] = *(const short8*)&Bs[(wc * WTN + cf * 16 + l16) * PAD +
                                      ks * 32 + hi8];
#pragma unroll
      for (int rf = 0; rf < FRM; rf++)
#pragma unroll
        for (int cf = 0; cf < FRN; cf++)
          acc[rf][cf] = __builtin_amdgcn_mfma_f32_16x16x32_bf16(
              af[rf], bfr[cf], acc[rf][cf], 0, 0, 0);
    }
  }
  long cb = b1 * sC1 + b2 * sC2;
#pragma unroll
  for (int rf = 0; rf < FRM; rf++) {
#pragma unroll
    for (int cf = 0; cf < FRN; cf++) {
      int col = n0 + wc * WTN + cf * 16 + l16;
#pragma unroll
      for (int j = 0; j < 4; j++) {
        int row = m0 + wr * WTM + rf * 16 + (l >> 4) * 4 + j;
        float v = acc[rf][cf][j];
        if (SCL) v *= scale;
        if (RELU) v = fmaxf(v, 0.f);
        long idx = (long)row * ldc + col;
        if (OBF) {
          ((short*)Cg + cb)[idx] = f2bf(v);
        } else {
          float* C = (float*)Cg + cb;
          if (ACC) v += C[idx];
          C[idx] = v;
        }
      }
    }
  }
}

// ---------------- fused logits (MFMA) + online LSE over vocab ----------------
// rows = 1024 of tmat_bf (x E), cols = G of embed_bf (G x E row-major = B^T).
// grid (NSPLIT_, 1024/64). Per block: 64 rows, chunk of 64 g-cols per iter.
__global__ __launch_bounds__(256) void lse_mfma_k(
    const short* __restrict__ tmat_bf, const short* __restrict__ embed_bf,
    float* __restrict__ mpart, float* __restrict__ spart) {
  constexpr int PAD = 264;  // 256 + 8
  __shared__ short As[64 * PAD];
  __shared__ short Bs[64 * PAD];
  int split = blockIdx.x, rb = blockIdx.y;
  int t = threadIdx.x;
  int w = t >> 6, l = t & 63;
  int l16 = l & 15, hi8 = (l >> 4) * 8;
  for (int i = t; i < 64 * 32; i += 256) {
    int r = i >> 5, c = (i & 31) * 8;
    *(short8*)&As[r * PAD + c] =
        *(const short8*)(tmat_bf + (long)(rb * 64 + r) * E_ + c);
  }
  float m[4], s[4];
#pragma unroll
  for (int j = 0; j < 4; j++) {
    m[j] = -1e30f;
    s[j] = 0.f;
  }
  const int NCH = G_ / 64;  // 500
  int c0 = split * NCH / NSPLIT_, c1 = (split + 1) * NCH / NSPLIT_;
  for (int ch = c0; ch < c1; ch++) {
    long g0 = (long)ch * 64;
    __syncthreads();
    for (int i = t; i < 64 * 32; i += 256) {
      int r = i >> 5, c = (i & 31) * 8;
      *(short8*)&Bs[r * PAD + c] =
          *(const short8*)(embed_bf + (g0 + r) * E_ + c);
    }
    __syncthreads();
    f32x4 acc[4];
#pragma unroll
    for (int cf = 0; cf < 4; cf++) acc[cf] = {0.f, 0.f, 0.f, 0.f};
#pragma unroll
    for (int ks = 0; ks < 8; ks++) {
      short8 a = *(const short8*)&As[(w * 16 + l16) * PAD + ks * 32 + hi8];
#pragma unroll
      for (int cf = 0; cf < 4; cf++) {
        short8 b = *(const short8*)&Bs[(cf * 16 + l16) * PAD + ks * 32 + hi8];
        acc[cf] = __builtin_amdgcn_mfma_f32_16x16x32_bf16(a, b, acc[cf], 0, 0, 0);
      }
    }
#pragma unroll
    for (int j = 0; j < 4; j++) {
      float vm = fmaxf(fmaxf(acc[0][j], acc[1][j]), fmaxf(acc[2][j], acc[3][j]));
      float mn = fmaxf(m[j], vm);
      s[j] = s[j] * __expf(m[j] - mn) + __expf(acc[0][j] - mn) +
             __expf(acc[1][j] - mn) + __expf(acc[2][j] - mn) +
             __expf(acc[3][j] - mn);
      m[j] = mn;
    }
  }
#pragma unroll
  for (int j = 0; j < 4; j++) {
#pragma unroll
    for (int mask = 1; mask <= 8; mask <<= 1) {
      float mo = __shfl_xor(m[j], mask, 64);
      float so = __shfl_xor(s[j], mask, 64);
      float mn = fmaxf(m[j], mo);
      s[j] = s[j] * __expf(m[j] - mn) + so * __expf(mo - mn);
      m[j] = mn;
    }
    if (l16 == 0) {
      int row = rb * 64 + w * 16 + (l >> 4) * 4 + j;
      mpart[row * NSPLIT_ + split] = m[j];
      spart[row * NSPLIT_ + split] = s[j];
    }
  }
}

// ---------------- conversion / small fused kernels ----------------
__global__ __launch_bounds__(256) void cvt_k(const float* __restrict__ src,
                                             short* __restrict__ dst, int n4) {
  int i = blockIdx.x * 256 + threadIdx.x;
  if (i < n4) {
    float4 v = ((const float4*)src)[i];
    short4v o = {f2bf(v.x), f2bf(v.y), f2bf(v.z), f2bf(v.w)};
    ((short4v*)dst)[i] = o;
  }
}

// (R,C) fp32 -> (C,R) bf16
__global__ __launch_bounds__(256) void trcvt_k(const float* __restrict__ src,
                                               short* __restrict__ dst, int R,
                                               int C) {
  __shared__ float tile[32][33];
  int c0 = blockIdx.x * 32, r0 = blockIdx.y * 32;
  int tx = threadIdx.x & 31, ty = threadIdx.x >> 5;  // ty 0..7
#pragma unroll
  for (int k = 0; k < 4; k++)
    tile[ty + k * 8][tx] = src[(long)(r0 + ty + k * 8) * C + c0 + tx];
  __syncthreads();
#pragma unroll
  for (int k = 0; k < 4; k++)
    dst[(long)(c0 + ty + k * 8) * R + r0 + tx] = f2bf(tile[tx][ty + k * 8]);
}

__global__ __launch_bounds__(256) void embed_init_k(
    const int* __restrict__ masked, const float* __restrict__ embed,
    const float* __restrict__ pos, float* __restrict__ xsa,
    short* __restrict__ xsa_bf, short* __restrict__ xsaT_bf) {
  int bl = blockIdx.x;
  int b = bl / L_, ll = bl % L_;
  int t = threadIdx.x;
  __shared__ float sm[4];
  int tok = masked[bl];
  float v = embed[(long)tok * E_ + t] + pos[(long)ll * E_ + t];
  float s1 = block_sum(v, sm);
  float s2 = block_sum(v * v, sm);
  float mean = s1 * (1.0f / E_);
  float var = (s2 - s1 * mean) * (1.0f / (E_ - 1));
  float xn = v / (1.0f + sqrtf(fmaxf(var, 0.f)));
  xsa[(long)bl * E_ + t] = xn;
  short h = f2bf(xn);
  xsa_bf[(long)bl * E_ + t] = h;
  xsaT_bf[((long)b * E_ + t) * L_ + ll] = h;
}

__global__ __launch_bounds__(256) void rollcvt_k(const float* __restrict__ xsa,
                                                 short* __restrict__ dst,
                                                 int shift) {
  int bl = blockIdx.x;
  int b = bl / L_, ll = bl % L_;
  int sl = (ll - shift + L_) % L_;
  dst[(long)bl * E_ + threadIdx.x] =
      f2bf(xsa[((long)b * L_ + sl) * E_ + threadIdx.x]);
}

// fp32 scores row -> softmax -> bf16 P written in-place over the row start
__global__ __launch_bounds__(256) void softmax_bf_k(float* __restrict__ x) {
  long row = blockIdx.x;
  float* p = x + row * (long)L_;
  short* pb = (short*)p;
  int t = threadIdx.x;
  __shared__ float sm[4];
  float v0 = p[t], v1 = p[t + 256];
  float mx = block_max(fmaxf(v0, v1), sm);
  float e0 = __expf(v0 - mx), e1 = __expf(v1 - mx);
  float s = block_sum(e0 + e1, sm);
  float inv = 1.0f / s;
  pb[t] = f2bf(e0 * inv);
  pb[t + 256] = f2bf(e1 * inv);
}

__global__ __launch_bounds__(256) void update_norm_k(
    float* __restrict__ xsa, const float* __restrict__ xsad,
    short* __restrict__ xsa_bf, short* __restrict__ xsaT_bf) {
  long r = blockIdx.x;
  int b = (int)(r / L_), ll = (int)(r % L_);
  int t = threadIdx.x;
  __shared__ float sm[4];
  float vd = xsad[r * E_ + t];
  float s1 = block_sum(vd, sm);
  float s2 = block_sum(vd * vd, sm);
  float mean = s1 * (1.0f / E_);
  float var = (s2 - s1 * mean) * (1.0f / (E_ - 1));
  float vdn = vd / (1.0f + sqrtf(fmaxf(var, 0.f)));
  float u = xsa[r * E_ + t] + STEP_ * vdn;
  s1 = block_sum(u, sm);
  s2 = block_sum(u * u, sm);
  mean = s1 * (1.0f / E_);
  var = (s2 - s1 * mean) * (1.0f / (E_ - 1));
  float xn = u / (1.0f + sqrtf(fmaxf(var, 0.f)));
  xsa[r * E_ + t] = xn;
  short h = f2bf(xn);
  xsa_bf[r * E_ + t] = h;
  xsaT_bf[((long)b * E_ + t) * L_ + ll] = h;
}

__global__ __launch_bounds__(256) void gather_k(const float* __restrict__ xsa,
                                                const int* __restrict__ mask,
                                                float* __restrict__ lptok) {
  int bm = blockIdx.x;
  int b = bm >> 6;
  int t = threadIdx.x;
  int p = mask[bm];
  lptok[(long)bm * E_ + t] = xsa[((long)b * L_ + p) * E_ + t];
}

// ---------------- fp32 tiled GEMM (small head matmuls only) ----------------
template <bool TRB, bool BIAS>
__global__ __launch_bounds__(256) void gemm_k(
    const float* __restrict__ Ag, const float* __restrict__ Bg,
    float* __restrict__ Cg, const float* __restrict__ bias, int M, int N,
    int Kd, int lda, int ldb, int ldc, long sA1, long sB1, long sC1) {
  constexpr int BM = 64, BN = 64, BK = 16, TM = 4, TN = 4;
  int b1 = blockIdx.z;
  const float* A = Ag + b1 * sA1;
  const float* Bp = Bg + b1 * sB1;
  float* C = Cg + b1 * sC1;
  int m0 = blockIdx.y * BM, n0 = blockIdx.x * BN;
  __shared__ float As[BK][BM + 4];
  __shared__ float Bs[BK][BN + 4];
  int t = threadIdx.x;
  int tx = t % (BN / TN), ty = t / (BN / TN);
  float acc[TM][TN];
#pragma unroll
  for (int i = 0; i < TM; i++)
#pragma unroll
    for (int j = 0; j < TN; j++) acc[i][j] = 0.f;
  for (int k0 = 0; k0 < Kd; k0 += BK) {
    __syncthreads();
    {
      int i = t;
      int r = i / (BK / 4), kc = (i % (BK / 4)) * 4;
      float4 v = *(const float4*)(A + (long)(m0 + r) * lda + k0 + kc);
      As[kc + 0][r] = v.x;
      As[kc + 1][r] = v.y;
      As[kc + 2][r] = v.z;
      As[kc + 3][r] = v.w;
    }
    if (!TRB) {
      int i = t;
      int r = i / (BN / 4), nc = (i % (BN / 4)) * 4;
      *(float4*)(&Bs[r][nc]) = *(const float4*)(Bp + (long)(k0 + r) * ldb + n0 + nc);
    } else {
      int i = t;
      int n = i / (BK / 4), kc = (i % (BK / 4)) * 4;
      float4 v = *(const float4*)(Bp + (long)(n0 + n) * ldb + k0 + kc);
      Bs[kc + 0][n] = v.x;
      Bs[kc + 1][n] = v.y;
      Bs[kc + 2][n] = v.z;
      Bs[kc + 3][n] = v.w;
    }
    __syncthreads();
#pragma unroll
    for (int kk = 0; kk < BK; kk++) {
      float a[TM], b[TN];
#pragma unroll
      for (int i = 0; i < TM; i++) a[i] = As[kk][ty * TM + i];
#pragma unroll
      for (int j = 0; j < TN; j++) b[j] = Bs[kk][tx * TN + j];
#pragma unroll
      for (int i = 0; i < TM; i++)
#pragma unroll
        for (int j = 0; j < TN; j++) acc[i][j] = fmaf(a[i], b[j], acc[i][j]);
    }
  }
#pragma unroll
  for (int i = 0; i < TM; i++) {
    long row = m0 + ty * TM + i;
    float* cp = C + row * (long)ldc + n0 + tx * TN;
#pragma unroll
    for (int j = 0; j < TN; j++) {
      float v = acc[i][j];
      if (BIAS) v += bias[n0 + tx * TN + j];
      cp[j] = v;
    }
  }
}

__global__ __launch_bounds__(256) void cent_k(
    const float* __restrict__ tmat, const float* __restrict__ embed,
    const int* __restrict__ mask, const int* __restrict__ unmasked,
    const float* __restrict__ mpart, const float* __restrict__ spart,
    float* __restrict__ cent) {
  int bm = blockIdx.x;
  int b = bm >> 6, m = bm & 63;
  int t = threadIdx.x;
  __shared__ float sm[4];
  __shared__ float tlv[KN_];
  int pos = mask[bm];
  int tgt = unmasked[b * L_ + pos];
  float ev = embed[(long)tgt * E_ + t];
  for (int kn = 0; kn < KN_; kn++) {
    long grow = (long)b * (M_ * KN_) + m * KN_ + kn;
    float dot = block_sum(tmat[grow * E_ + t] * ev, sm);
    if (t == 0) {
      float M = -1e30f, S = 0.f;
      for (int i = 0; i < NSPLIT_; i++) {
        float m2 = mpart[grow * NSPLIT_ + i], s2 = spart[grow * NSPLIT_ + i];
        float MM = fmaxf(M, m2);
        S = S * __expf(M - MM) + s2 * __expf(m2 - MM);
        M = MM;
      }
      tlv[kn] = dot - (M + __logf(S));
    }
  }
  __syncthreads();
  if (t == 0) {
    float mx = fmaxf(fmaxf(tlv[0], tlv[1]), fmaxf(tlv[2], tlv[3]));
    float s = __expf(tlv[0] - mx) + __expf(tlv[1] - mx) + __expf(tlv[2] - mx) +
              __expf(tlv[3] - mx);
    cent[bm] = __logf(s) + mx - 1.3862943611198906f;
  }
}

__global__ __launch_bounds__(256) void loss_k(const float* __restrict__ cent,
                                              const float* __restrict__ summer,
                                              float* __restrict__ out) {
  int t = threadIdx.x;
  int b = t >> 6, m = t & 63;
  float c = cent[b * 64 + m], su = summer[b * 64 + m];
  float num = wsum(c * su);
  float den = wsum(su);
  if (m == 0) out[b] = -num / fmaxf(den, 1.0f);
}

// ---------------- launcher ----------------
extern "C" void kernel_launch(void* const* d_in, const int* in_sizes, int n_in,
                              void* d_out, int out_size, void* d_ws,
                              size_t ws_size, hipStream_t stream) {
  (void)in_sizes; (void)n_in; (void)out_size; (void)ws_size;
  const int* masked = (const int*)d_in[0];
  const int* unmasked = (const int*)d_in[1];
  const int* mask = (const int*)d_in[2];
  const float* summer = (const float*)d_in[3];
  const float* embed = (const float*)d_in[4];
  const float* pos = (const float*)d_in[5];
  const float* Wt = (const float*)d_in[6];
  const float* Wc = (const float*)d_in[7];
  const float* Wq = (const float*)d_in[8];
  const float* Wd = (const float*)d_in[9];
  const float* Wo = (const float*)d_in[10];
  const float* Wkc = (const float*)d_in[11];
  const float* bkc = (const float*)d_in[12];
  const float* Wem = (const float*)d_in[13];
  float* out = (float*)d_out;

  char* p = (char*)d_ws;
  auto take = [&](size_t bytes) {
    char* r = p;
    p += (bytes + 255) & ~(size_t)255;
    return r;
  };
  float* xsa = (float*)take((size_t)BL_ * E_ * 4);
  float* xsad = (float*)take((size_t)BL_ * E_ * 4);
  short* xsa_bf = (short*)take((size_t)BL_ * E_ * 2);
  short* xsaT_bf = (short*)take((size_t)BL_ * E_ * 2);
  short* rolled_bf = (short*)take((size_t)BL_ * E_ * 2);
  short* t1_bf = (short*)take((size_t)BL_ * E_ * 2);
  short* q_bf = (short*)take((size_t)BL_ * KE_ * 2);  // also reused as xid
  short* y_bf = (short*)take((size_t)BL_ * KE_ * 2);
  short* wt_bf = (short*)take((size_t)E_ * E_ * 2);
  short* wtT_bf = (short*)take((size_t)E_ * E_ * 2);
  short* wc_bf = (short*)take((size_t)E_ * E_ * 2);
  short* wcT_bf = (short*)take((size_t)E_ * E_ * 2);
  short* wq_bf = (short*)take((size_t)KE_ * E_ * 2);
  short* wd_bf = (short*)take((size_t)KE_ * KE_ * 2);
  short* woT_bf = (short*)take((size_t)KE_ * E_ * 2);
  char* big = take((size_t)B_ * K_ * L_ * L_ * 4);  // 32 MB shared region
  float* sc = (float*)big;                          // layers: scores / P
  // head aliases (used only after the layer loop):
  char* hp = big;
  auto htake = [&](size_t bytes) {
    char* r = hp;
    hp += (bytes + 255) & ~(size_t)255;
    return r;
  };
  short* embed_bf = (short*)htake((size_t)G_ * E_ * 2);
  float* lptok = (float*)htake((size_t)B_ * M_ * E_ * 4);
  float* xx1 = (float*)htake((size_t)B_ * M_ * KN_ * E_ * 4);
  float* xx2 = (float*)htake((size_t)B_ * M_ * KN_ * L_ * 4);
  float* xx3 = (float*)htake((size_t)B_ * M_ * KN_ * E_ * 4);
  float* tmat = (float*)htake((size_t)B_ * M_ * KN_ * E_ * 4);
  short* tmat_bf = (short*)htake((size_t)B_ * M_ * KN_ * E_ * 2);
  float* mpart = (float*)htake((size_t)1024 * NSPLIT_ * 4);
  float* spart = (float*)htake((size_t)1024 * NSPLIT_ * 4);
  float* cent = (float*)htake((size_t)B_ * M_ * 4);

  dim3 blk(256);
  embed_init_k<<<BL_, blk, 0, stream>>>(masked, embed, pos, xsa, xsa_bf, xsaT_bf);

  for (int d = 0; d < D_; d++) {
    const float* Wt_d = Wt + (long)d * E_ * E_;
    const float* Wc_d = Wc + (long)d * E_ * E_;
    const float* Wq_d = Wq + (long)d * KE_ * E_;
    const float* Wd_d = Wd + (long)d * KE_ * KE_;
    const float* Wo_d = Wo + (long)d * KE_ * E_;
    // per-layer weight conversions
    cvt_k<<<64, blk, 0, stream>>>(Wt_d, wt_bf, E_ * E_ / 4);
    cvt_k<<<64, blk, 0, stream>>>(Wc_d, wc_bf, E_ * E_ / 4);
    cvt_k<<<512, blk, 0, stream>>>(Wq_d, wq_bf, KE_ * E_ / 4);
    cvt_k<<<4096, blk, 0, stream>>>(Wd_d, wd_bf, KE_ * KE_ / 4);
    trcvt_k<<<dim3(8, 8), blk, 0, stream>>>(Wt_d, wtT_bf, E_, E_);
    trcvt_k<<<dim3(8, 8), blk, 0, stream>>>(Wc_d, wcT_bf, E_, E_);
    trcvt_k<<<dim3(8, 64), blk, 0, stream>>>(Wo_d, woT_bf, KE_, E_);

    // local transition chain
    rollcvt_k<<<BL_, blk, 0, stream>>>(xsa, rolled_bf, 1);
    mgemm_k<64, 64, true, false, false, true><<<dim3(4, 32, 1), blk, 0, stream>>>(
        rolled_bf, wtT_bf, t1_bf, 1.f, E_, E_, E_, E_, 1, 0, 0, 0, 0, 0, 0);
    mgemm_k<64, 64, false, false, false, false><<<dim3(4, 32, 1), blk, 0, stream>>>(
        t1_bf, wcT_bf, xsad, 1.f, E_, E_, E_, E_, 1, 0, 0, 0, 0, 0, 0);
    rollcvt_k<<<BL_, blk, 0, stream>>>(xsa, rolled_bf, -1);
    mgemm_k<64, 64, true, false, false, true><<<dim3(4, 32, 1), blk, 0, stream>>>(
        rolled_bf, wc_bf, t1_bf, 1.f, E_, E_, E_, E_, 1, 0, 0, 0, 0, 0, 0);
    mgemm_k<64, 64, false, true, false, false><<<dim3(4, 32, 1), blk, 0, stream>>>(
        t1_bf, wt_bf, xsad, 1.f, E_, E_, E_, E_, 1, 0, 0, 0, 0, 0, 0);

    // q = xsa @ Wq^T
    mgemm_k<64, 128, false, false, false, true><<<dim3(16, 32, 1), blk, 0, stream>>>(
        xsa_bf, wq_bf, q_bf, 1.f, E_, E_, E_, KE_, 1, 0, 0, 0, 0, 0, 0);
    // scores = q @ xsa^T / 16  (fp32)
    mgemm_k<128, 128, false, false, true, false><<<dim3(4, 4, B_ * K_), blk, 0, stream>>>(
        q_bf, xsa_bf, sc, 0.0625f, E_, KE_, E_, L_, K_, (long)L_ * KE_, E_,
        (long)L_ * E_, 0, (long)K_ * L_ * L_, (long)L_ * L_);
    softmax_bf_k<<<B_ * K_ * L_, blk, 0, stream>>>(sc);
    // yik = P @ xsa  (P bf16 in-place in sc rows, B^T = xsaT)
    mgemm_k<64, 128, false, false, false, true><<<dim3(2, 8, B_ * K_), blk, 0, stream>>>(
        (const short*)sc, xsaT_bf, y_bf, 1.f, L_, L_ * 2, L_, KE_, K_,
        (long)K_ * L_ * L_ * 2, (long)L_ * L_ * 2, (long)E_ * L_, 0,
        (long)L_ * KE_, E_);
    // xid = relu(yik @ Wd^T)   (into q_bf)
    mgemm_k<64, 128, true, false, false, true><<<dim3(16, 32, 1), blk, 0, stream>>>(
        y_bf, wd_bf, q_bf, 1.f, KE_, KE_, KE_, KE_, 1, 0, 0, 0, 0, 0, 0);
    // xsad += xid @ Wo
    mgemm_k<64, 64, false, true, false, false><<<dim3(4, 32, 1), blk, 0, stream>>>(
        q_bf, woT_bf, xsad, 1.f, KE_, KE_, KE_, E_, 1, 0, 0, 0, 0, 0, 0);

    update_norm_k<<<BL_, blk, 0, stream>>>(xsa, xsad, xsa_bf, xsaT_bf);
  }

  // ---- loss head (fp32 small GEMMs, then MFMA LSE) ----
  gather_k<<<B_ * M_, blk, 0, stream>>>(xsa, mask, lptok);
  gemm_k<true, true><<<dim3(16, 4, 1), blk, 0, stream>>>(
      lptok, Wkc, xx1, bkc, B_ * M_, KN_ * E_, E_, E_, E_, KN_ * E_, 0, 0, 0);
  gemm_k<true, false><<<dim3(8, 4, B_), blk, 0, stream>>>(
      xx1, xsa, xx2, nullptr, M_ * KN_, L_, E_, E_, E_, L_,
      (long)M_ * KN_ * E_, (long)L_ * E_, (long)M_ * KN_ * L_);
  gemm_k<false, false><<<dim3(4, 4, B_), blk, 0, stream>>>(
      xx2, xsa, xx3, nullptr, M_ * KN_, E_, L_, L_, E_, E_,
      (long)M_ * KN_ * L_, (long)L_ * E_, (long)M_ * KN_ * E_);
  gemm_k<false, false><<<dim3(4, 4, B_), blk, 0, stream>>>(
      xx3, Wem, tmat, nullptr, M_ * KN_, E_, E_, E_, E_, E_,
      (long)M_ * KN_ * E_, 0, (long)M_ * KN_ * E_);
  cvt_k<<<8000, blk, 0, stream>>>(embed, embed_bf, G_ * E_ / 4);
  cvt_k<<<256, blk, 0, stream>>>(tmat, tmat_bf, B_ * M_ * KN_ * E_ / 4);
  lse_mfma_k<<<dim3(NSPLIT_, 16), blk, 0, stream>>>(tmat_bf, embed_bf, mpart, spart);
  cent_k<<<B_ * M_, blk, 0, stream>>>(tmat, embed, mask, unmasked, mpart, spart, cent);
  loss_k<<<1, blk, 0, stream>>>(cent, summer, out);
}

// Round 3
// 1318.040 us; speedup vs baseline: 3.2725x; 1.1819x over previous
//
#include <hip/hip_runtime.h>
#include <math.h>
#include <stdint.h>

#define G_ 32000
#define E_ 256
#define K_ 8
#define D_ 6
#define B_ 4
#define L_ 512
#define M_ 64
#define KN_ 4
#define STEP_ 0.05f
#define BL_ (B_ * L_)   // 2048
#define KE_ (K_ * E_)   // 2048
#define NSPLIT_ 50
#define GCH_ 10         // 64-col chunks per split: 50*10*64 = 32000

typedef __attribute__((ext_vector_type(8))) short short8;
typedef __attribute__((ext_vector_type(4))) float f32x4;
typedef __attribute__((ext_vector_type(4))) short short4v;

__device__ __forceinline__ short f2bf(float f) {
  unsigned u = __builtin_bit_cast(unsigned, f);
  unsigned r = (u + 0x7fffu + ((u >> 16) & 1u)) >> 16;
  return (short)r;
}

__device__ __forceinline__ void gload16(const void* g, void* l) {
  __builtin_amdgcn_global_load_lds(
      reinterpret_cast<const __attribute__((address_space(1))) void*>(
          reinterpret_cast<uintptr_t>(g)),
      reinterpret_cast<__attribute__((address_space(3))) void*>(
          reinterpret_cast<uintptr_t>(l)),
      16, 0, 0);
}

// ---------------- reduction helpers ----------------
__device__ __forceinline__ float wsum(float v) {
#pragma unroll
  for (int o = 32; o > 0; o >>= 1) v += __shfl_xor(v, o, 64);
  return v;
}
__device__ __forceinline__ float block_sum(float v, float* sm) {
  v = wsum(v);
  int wid = threadIdx.x >> 6, lane = threadIdx.x & 63;
  if (lane == 0) sm[wid] = v;
  __syncthreads();
  float r = sm[0] + sm[1] + sm[2] + sm[3];
  __syncthreads();
  return r;
}
__device__ __forceinline__ float wmax(float v) {
#pragma unroll
  for (int o = 32; o > 0; o >>= 1) v = fmaxf(v, __shfl_xor(v, o, 64));
  return v;
}
__device__ __forceinline__ float block_max(float v, float* sm) {
  v = wmax(v);
  int wid = threadIdx.x >> 6, lane = threadIdx.x & 63;
  if (lane == 0) sm[wid] = v;
  __syncthreads();
  float r = fmaxf(fmaxf(sm[0], sm[1]), fmaxf(sm[2], sm[3]));
  __syncthreads();
  return r;
}

// ---------------- 128x128 MFMA GEMM (m97 structure) ----------------
// C[M,N] = A[M,K] @ B^T, B stored (N,K) bf16. BK=64, global_load_lds staging,
// XOR-swizzled LDS (linear dest + inverse-swizzled global source).
// 4 waves 2x2, each wave 64x64 (4x4 frags of 16x16x32).
// ROLL: roll A's row within each L_-periodic segment (jnp.roll semantics).
template <bool RELU, bool ACC, bool SCL, bool OBF, int ROLL>
__global__ __launch_bounds__(256) void mg128_k(
    const short* __restrict__ Ag, const short* __restrict__ Bg,
    void* __restrict__ Cg, float scale, int Kd, int lda, int ldb, int ldc,
    int batch2, long sA1, long sA2, long sB1, long sB2, long sC1, long sC2) {
  __shared__ short As[128 * 64];
  __shared__ short Bs[128 * 64];
  int bz = blockIdx.z;
  int b1 = bz / batch2, b2 = bz - b1 * batch2;
  const short* A = Ag + b1 * sA1 + b2 * sA2;
  const short* B = Bg + b1 * sB1 + b2 * sB2;
  int m0 = blockIdx.y * 128, n0 = blockIdx.x * 128;
  int t = threadIdx.x, w = t >> 6, l = t & 63;
  int l16 = l & 15, qd = l >> 4, hi8 = qd * 8;
  int wr = w >> 1, wc = w & 1;
  int sr = l >> 3;                        // sub-row within 8-row group
  int scol = ((l & 7) * 8) ^ (sr << 3);   // inverse-swizzled source col (shorts)
  f32x4 acc[4][4];
#pragma unroll
  for (int i = 0; i < 4; i++)
#pragma unroll
    for (int j = 0; j < 4; j++) acc[i][j] = {0.f, 0.f, 0.f, 0.f};

  for (int k0 = 0; k0 < Kd; k0 += 64) {
    __syncthreads();
#pragma unroll
    for (int c = 0; c < 4; c++) {
      int sub = w * 4 + c;
      int r = sub * 8 + sr;
      int gr = m0 + r;
      if (ROLL != 0) {
        int bb = gr >> 9, pp = gr & (L_ - 1);
        gr = (bb << 9) | ((pp - ROLL + L_) & (L_ - 1));
      }
      gload16(A + (long)gr * lda + k0 + scol, &As[sub * 512]);
    }
#pragma unroll
    for (int c = 0; c < 4; c++) {
      int sub = w * 4 + c;
      int r = sub * 8 + sr;
      gload16(B + (long)(n0 + r) * ldb + k0 + scol, &Bs[sub * 512]);
    }
    __syncthreads();
#pragma unroll
    for (int ks = 0; ks < 2; ks++) {
      short8 af[4], bf[4];
#pragma unroll
      for (int rf = 0; rf < 4; rf++) {
        int row = wr * 64 + rf * 16 + l16;
        af[rf] = *(const short8*)&As[(row * 64 + ks * 32 + hi8) ^ ((row & 7) << 3)];
      }
#pragma unroll
      for (int cf = 0; cf < 4; cf++) {
        int row = wc * 64 + cf * 16 + l16;
        bf[cf] = *(const short8*)&Bs[(row * 64 + ks * 32 + hi8) ^ ((row & 7) << 3)];
      }
#pragma unroll
      for (int rf = 0; rf < 4; rf++)
#pragma unroll
        for (int cf = 0; cf < 4; cf++)
          acc[rf][cf] = __builtin_amdgcn_mfma_f32_16x16x32_bf16(
              af[rf], bf[cf], acc[rf][cf], 0, 0, 0);
    }
  }
  long cb = b1 * sC1 + b2 * sC2;
#pragma unroll
  for (int rf = 0; rf < 4; rf++) {
#pragma unroll
    for (int cf = 0; cf < 4; cf++) {
      int col = n0 + wc * 64 + cf * 16 + l16;
#pragma unroll
      for (int j = 0; j < 4; j++) {
        int row = m0 + wr * 64 + rf * 16 + qd * 4 + j;
        float v = acc[rf][cf][j];
        if (SCL) v *= scale;
        if (RELU) v = fmaxf(v, 0.f);
        long idx = (long)row * ldc + col;
        if (OBF) {
          ((short*)Cg + cb)[idx] = f2bf(v);
        } else {
          float* C = (float*)Cg + cb;
          if (ACC) v += C[idx];
          C[idx] = v;
        }
      }
    }
  }
}

// ---------------- fused logits (MFMA, A-in-registers) + online LSE ----------
// rows: 1024 of tmat_bf; cols: G of embed_bf (G,E) = B^T form.
// grid (NSPLIT_, 16). Block: 64 rows; GCH_ chunks of 64 cols.
__global__ __launch_bounds__(256) void lse2_k(
    const short* __restrict__ tmat_bf, const short* __restrict__ embed_bf,
    float* __restrict__ mpart, float* __restrict__ spart) {
  __shared__ short Bs[64 * 256];  // 32 KB
  int split = blockIdx.x, rb = blockIdx.y;
  int t = threadIdx.x, w = t >> 6, l = t & 63;
  int l16 = l & 15, qd = l >> 4, hi8 = qd * 8;
  short8 areg[8];
  {
    const short* ar = tmat_bf + (long)(rb * 64 + w * 16 + l16) * E_;
#pragma unroll
    for (int ks = 0; ks < 8; ks++) areg[ks] = *(const short8*)(ar + ks * 32 + hi8);
  }
  float m[4], s[4];
#pragma unroll
  for (int j = 0; j < 4; j++) {
    m[j] = -1e30f;
    s[j] = 0.f;
  }
  long gbase = (long)split * (GCH_ * 64);
  for (int ch = 0; ch < GCH_; ch++) {
    long g0 = gbase + ch * 64;
    __syncthreads();
#pragma unroll
    for (int j = 0; j < 8; j++) {
      int sub = w * 8 + j;
      int r = sub * 2 + (l >> 5);
      int r7 = r & 7;
      int col = ((l & 31) * 8) ^ (r7 << 3);
      gload16(embed_bf + (g0 + r) * E_ + col, &Bs[sub * 512]);
    }
    __syncthreads();
    f32x4 acc[4];
#pragma unroll
    for (int cf = 0; cf < 4; cf++) acc[cf] = {0.f, 0.f, 0.f, 0.f};
#pragma unroll
    for (int ks = 0; ks < 8; ks++) {
#pragma unroll
      for (int cf = 0; cf < 4; cf++) {
        int row = cf * 16 + l16;
        short8 b = *(const short8*)&Bs[(row * 256 + ks * 32 + hi8) ^ ((row & 7) << 3)];
        acc[cf] = __builtin_amdgcn_mfma_f32_16x16x32_bf16(areg[ks], b, acc[cf], 0, 0, 0);
      }
    }
#pragma unroll
    for (int j = 0; j < 4; j++) {
      float vm = fmaxf(fmaxf(acc[0][j], acc[1][j]), fmaxf(acc[2][j], acc[3][j]));
      float mn = fmaxf(m[j], vm);
      s[j] = s[j] * __expf(m[j] - mn) + __expf(acc[0][j] - mn) +
             __expf(acc[1][j] - mn) + __expf(acc[2][j] - mn) +
             __expf(acc[3][j] - mn);
      m[j] = mn;
    }
  }
#pragma unroll
  for (int j = 0; j < 4; j++) {
#pragma unroll
    for (int mask = 1; mask <= 8; mask <<= 1) {
      float mo = __shfl_xor(m[j], mask, 64);
      float so = __shfl_xor(s[j], mask, 64);
      float mn = fmaxf(m[j], mo);
      s[j] = s[j] * __expf(m[j] - mn) + so * __expf(mo - mn);
      m[j] = mn;
    }
    if (l16 == 0) {
      int row = rb * 64 + w * 16 + qd * 4 + j;
      mpart[(long)row * NSPLIT_ + split] = m[j];
      spart[(long)row * NSPLIT_ + split] = s[j];
    }
  }
}

// ---------------- fused per-layer weight conversion ----------------
__device__ __forceinline__ void cvt_blk(const float* __restrict__ src,
                                        short* __restrict__ dst, int blk, int t) {
  int i = blk * 256 + t;
  float4 v = ((const float4*)src)[i];
  short4v o = {f2bf(v.x), f2bf(v.y), f2bf(v.z), f2bf(v.w)};
  ((short4v*)dst)[i] = o;
}
__device__ __forceinline__ void trans_blk(const float* __restrict__ src,
                                          short* __restrict__ dst, int bx, int by,
                                          int R, int C, float (*tile)[33], int t) {
  int c0 = bx * 32, r0 = by * 32;
  int tx = t & 31, ty = t >> 5;
#pragma unroll
  for (int k = 0; k < 4; k++)
    tile[ty + k * 8][tx] = src[(long)(r0 + ty + k * 8) * C + c0 + tx];
  __syncthreads();
#pragma unroll
  for (int k = 0; k < 4; k++)
    dst[(long)(c0 + ty + k * 8) * R + r0 + tx] = f2bf(tile[tx][ty + k * 8]);
}
// grid: 4096 wd | 512 wq | 64 wt | 64 wc | 64 wtT | 64 wcT | 512 woT = 5376
__global__ __launch_bounds__(256) void wcvt_k(
    const float* __restrict__ Wt_d, const float* __restrict__ Wc_d,
    const float* __restrict__ Wq_d, const float* __restrict__ Wd_d,
    const float* __restrict__ Wo_d, short* wt, short* wc, short* wq, short* wd,
    short* wtT, short* wcT, short* woT) {
  __shared__ float tile[32][33];
  int blk = blockIdx.x, t = threadIdx.x;
  if (blk < 4096) { cvt_blk(Wd_d, wd, blk, t); return; }
  blk -= 4096;
  if (blk < 512) { cvt_blk(Wq_d, wq, blk, t); return; }
  blk -= 512;
  if (blk < 64) { cvt_blk(Wt_d, wt, blk, t); return; }
  blk -= 64;
  if (blk < 64) { cvt_blk(Wc_d, wc, blk, t); return; }
  blk -= 64;
  if (blk < 64) { trans_blk(Wt_d, wtT, blk & 7, blk >> 3, E_, E_, tile, t); return; }
  blk -= 64;
  if (blk < 64) { trans_blk(Wc_d, wcT, blk & 7, blk >> 3, E_, E_, tile, t); return; }
  blk -= 64;
  trans_blk(Wo_d, woT, blk & 7, blk >> 3, KE_, E_, tile, t);
}

// ---------------- small fused kernels ----------------
__global__ __launch_bounds__(256) void cvt_k(const float* __restrict__ src,
                                             short* __restrict__ dst, int n4) {
  int i = blockIdx.x * 256 + threadIdx.x;
  if (i < n4) {
    float4 v = ((const float4*)src)[i];
    short4v o = {f2bf(v.x), f2bf(v.y), f2bf(v.z), f2bf(v.w)};
    ((short4v*)dst)[i] = o;
  }
}

__global__ __launch_bounds__(256) void embed_init_k(
    const int* __restrict__ masked, const float* __restrict__ embed,
    const float* __restrict__ pos, float* __restrict__ xsa,
    short* __restrict__ xsa_bf, short* __restrict__ xsaT_bf) {
  int bl = blockIdx.x;
  int b = bl / L_, ll = bl % L_;
  int t = threadIdx.x;
  __shared__ float sm[4];
  int tok = masked[bl];
  float v = embed[(long)tok * E_ + t] + pos[(long)ll * E_ + t];
  float s1 = block_sum(v, sm);
  float s2 = block_sum(v * v, sm);
  float mean = s1 * (1.0f / E_);
  float var = (s2 - s1 * mean) * (1.0f / (E_ - 1));
  float xn = v / (1.0f + sqrtf(fmaxf(var, 0.f)));
  xsa[(long)bl * E_ + t] = xn;
  short h = f2bf(xn);
  xsa_bf[(long)bl * E_ + t] = h;
  xsaT_bf[((long)b * E_ + t) * L_ + ll] = h;
}

__global__ __launch_bounds__(256) void softmax_bf_k(float* __restrict__ x) {
  long row = blockIdx.x;
  float* p = x + row * (long)L_;
  short* pb = (short*)p;
  int t = threadIdx.x;
  __shared__ float sm[4];
  float v0 = p[t], v1 = p[t + 256];
  float mx = block_max(fmaxf(v0, v1), sm);
  float e0 = __expf(v0 - mx), e1 = __expf(v1 - mx);
  float s = block_sum(e0 + e1, sm);
  float inv = 1.0f / s;
  pb[t] = f2bf(e0 * inv);
  pb[t + 256] = f2bf(e1 * inv);
}

__global__ __launch_bounds__(256) void update_norm_k(
    float* __restrict__ xsa, const float* __restrict__ xsad,
    short* __restrict__ xsa_bf, short* __restrict__ xsaT_bf) {
  long r = blockIdx.x;
  int b = (int)(r / L_), ll = (int)(r % L_);
  int t = threadIdx.x;
  __shared__ float sm[4];
  float vd = xsad[r * E_ + t];
  float s1 = block_sum(vd, sm);
  float s2 = block_sum(vd * vd, sm);
  float mean = s1 * (1.0f / E_);
  float var = (s2 - s1 * mean) * (1.0f / (E_ - 1));
  float vdn = vd / (1.0f + sqrtf(fmaxf(var, 0.f)));
  float u = xsa[r * E_ + t] + STEP_ * vdn;
  s1 = block_sum(u, sm);
  s2 = block_sum(u * u, sm);
  mean = s1 * (1.0f / E_);
  var = (s2 - s1 * mean) * (1.0f / (E_ - 1));
  float xn = u / (1.0f + sqrtf(fmaxf(var, 0.f)));
  xsa[r * E_ + t] = xn;
  short h = f2bf(xn);
  xsa_bf[r * E_ + t] = h;
  xsaT_bf[((long)b * E_ + t) * L_ + ll] = h;
}

__global__ __launch_bounds__(256) void gather_k(const float* __restrict__ xsa,
                                                const int* __restrict__ mask,
                                                float* __restrict__ lptok) {
  int bm = blockIdx.x;
  int b = bm >> 6;
  int t = threadIdx.x;
  int p = mask[bm];
  lptok[(long)bm * E_ + t] = xsa[((long)b * L_ + p) * E_ + t];
}

// ---------------- fp32 tiled GEMM (small head matmuls) ----------------
template <bool TRB, bool BIAS>
__global__ __launch_bounds__(256) void gemm_k(
    const float* __restrict__ Ag, const float* __restrict__ Bg,
    float* __restrict__ Cg, const float* __restrict__ bias, int M, int N,
    int Kd, int lda, int ldb, int ldc, long sA1, long sB1, long sC1) {
  constexpr int BM = 64, BN = 64, BK = 16, TM = 4, TN = 4;
  int b1 = blockIdx.z;
  const float* A = Ag + b1 * sA1;
  const float* Bp = Bg + b1 * sB1;
  float* C = Cg + b1 * sC1;
  int m0 = blockIdx.y * BM, n0 = blockIdx.x * BN;
  __shared__ float As[BK][BM + 4];
  __shared__ float Bs[BK][BN + 4];
  int t = threadIdx.x;
  int tx = t % (BN / TN), ty = t / (BN / TN);
  float acc[TM][TN];
#pragma unroll
  for (int i = 0; i < TM; i++)
#pragma unroll
    for (int j = 0; j < TN; j++) acc[i][j] = 0.f;
  for (int k0 = 0; k0 < Kd; k0 += BK) {
    __syncthreads();
    {
      int r = t / (BK / 4), kc = (t % (BK / 4)) * 4;
      float4 v = *(const float4*)(A + (long)(m0 + r) * lda + k0 + kc);
      As[kc + 0][r] = v.x;
      As[kc + 1][r] = v.y;
      As[kc + 2][r] = v.z;
      As[kc + 3][r] = v.w;
    }
    if (!TRB) {
      int r = t / (BN / 4), nc = (t % (BN / 4)) * 4;
      *(float4*)(&Bs[r][nc]) = *(const float4*)(Bp + (long)(k0 + r) * ldb + n0 + nc);
    } else {
      int n = t / (BK / 4), kc = (t % (BK / 4)) * 4;
      float4 v = *(const float4*)(Bp + (long)(n0 + n) * ldb + k0 + kc);
      Bs[kc + 0][n] = v.x;
      Bs[kc + 1][n] = v.y;
      Bs[kc + 2][n] = v.z;
      Bs[kc + 3][n] = v.w;
    }
    __syncthreads();
#pragma unroll
    for (int kk = 0; kk < BK; kk++) {
      float a[TM], b[TN];
#pragma unroll
      for (int i = 0; i < TM; i++) a[i] = As[kk][ty * TM + i];
#pragma unroll
      for (int j = 0; j < TN; j++) b[j] = Bs[kk][tx * TN + j];
#pragma unroll
      for (int i = 0; i < TM; i++)
#pragma unroll
        for (int j = 0; j < TN; j++) acc[i][j] = fmaf(a[i], b[j], acc[i][j]);
    }
  }
#pragma unroll
  for (int i = 0; i < TM; i++) {
    long row = m0 + ty * TM + i;
    float* cp = C + row * (long)ldc + n0 + tx * TN;
#pragma unroll
    for (int j = 0; j < TN; j++) {
      float v = acc[i][j];
      if (BIAS) v += bias[n0 + tx * TN + j];
      cp[j] = v;
    }
  }
}

__global__ __launch_bounds__(256) void cent_k(
    const float* __restrict__ tmat, const float* __restrict__ embed,
    const int* __restrict__ mask, const int* __restrict__ unmasked,
    const float* __restrict__ mpart, const float* __restrict__ spart,
    float* __restrict__ cent) {
  int bm = blockIdx.x;
  int b = bm >> 6, m = bm & 63;
  int t = threadIdx.x;
  __shared__ float sm[4];
  __shared__ float tlv[KN_];
  int pos = mask[bm];
  int tgt = unmasked[b * L_ + pos];
  float ev = embed[(long)tgt * E_ + t];
  for (int kn = 0; kn < KN_; kn++) {
    long grow = (long)b * (M_ * KN_) + m * KN_ + kn;
    float dot = block_sum(tmat[grow * E_ + t] * ev, sm);
    if (t == 0) {
      float M = -1e30f, S = 0.f;
      for (int i = 0; i < NSPLIT_; i++) {
        float m2 = mpart[grow * NSPLIT_ + i], s2 = spart[grow * NSPLIT_ + i];
        float MM = fmaxf(M, m2);
        S = S * __expf(M - MM) + s2 * __expf(m2 - MM);
        M = MM;
      }
      tlv[kn] = dot - (M + __logf(S));
    }
  }
  __syncthreads();
  if (t == 0) {
    float mx = fmaxf(fmaxf(tlv[0], tlv[1]), fmaxf(tlv[2], tlv[3]));
    float s = __expf(tlv[0] - mx) + __expf(tlv[1] - mx) + __expf(tlv[2] - mx) +
              __expf(tlv[3] - mx);
    cent[bm] = __logf(s) + mx - 1.3862943611198906f;
  }
}

__global__ __launch_bounds__(256) void loss_k(const float* __restrict__ cent,
                                              const float* __restrict__ summer,
                                              float* __restrict__ out) {
  int t = threadIdx.x;
  int b = t >> 6, m = t & 63;
  float c = cent[b * 64 + m], su = summer[b * 64 + m];
  float num = wsum(c * su);
  float den = wsum(su);
  if (m == 0) out[b] = -num / fmaxf(den, 1.0f);
}

// ---------------- launcher ----------------
extern "C" void kernel_launch(void* const* d_in, const int* in_sizes, int n_in,
                              void* d_out, int out_size, void* d_ws,
                              size_t ws_size, hipStream_t stream) {
  (void)in_sizes; (void)n_in; (void)out_size; (void)ws_size;
  const int* masked = (const int*)d_in[0];
  const int* unmasked = (const int*)d_in[1];
  const int* mask = (const int*)d_in[2];
  const float* summer = (const float*)d_in[3];
  const float* embed = (const float*)d_in[4];
  const float* pos = (const float*)d_in[5];
  const float* Wt = (const float*)d_in[6];
  const float* Wc = (const float*)d_in[7];
  const float* Wq = (const float*)d_in[8];
  const float* Wd = (const float*)d_in[9];
  const float* Wo = (const float*)d_in[10];
  const float* Wkc = (const float*)d_in[11];
  const float* bkc = (const float*)d_in[12];
  const float* Wem = (const float*)d_in[13];
  float* out = (float*)d_out;

  char* p = (char*)d_ws;
  auto take = [&](size_t bytes) {
    char* r = p;
    p += (bytes + 255) & ~(size_t)255;
    return r;
  };
  float* xsa = (float*)take((size_t)BL_ * E_ * 4);
  float* xsad = (float*)take((size_t)BL_ * E_ * 4);
  short* xsa_bf = (short*)take((size_t)BL_ * E_ * 2);
  short* xsaT_bf = (short*)take((size_t)BL_ * E_ * 2);
  short* t1_bf = (short*)take((size_t)BL_ * E_ * 2);
  short* q_bf = (short*)take((size_t)BL_ * KE_ * 2);  // reused as xid
  short* y_bf = (short*)take((size_t)BL_ * KE_ * 2);
  short* wt_bf = (short*)take((size_t)E_ * E_ * 2);
  short* wtT_bf = (short*)take((size_t)E_ * E_ * 2);
  short* wc_bf = (short*)take((size_t)E_ * E_ * 2);
  short* wcT_bf = (short*)take((size_t)E_ * E_ * 2);
  short* wq_bf = (short*)take((size_t)KE_ * E_ * 2);
  short* wd_bf = (short*)take((size_t)KE_ * KE_ * 2);
  short* woT_bf = (short*)take((size_t)KE_ * E_ * 2);
  char* big = take((size_t)B_ * K_ * L_ * L_ * 4);  // 33.5 MB shared region
  float* sc = (float*)big;
  char* hp = big;
  auto htake = [&](size_t bytes) {
    char* r = hp;
    hp += (bytes + 255) & ~(size_t)255;
    return r;
  };
  short* embed_bf = (short*)htake((size_t)G_ * E_ * 2);
  float* lptok = (float*)htake((size_t)B_ * M_ * E_ * 4);
  float* xx1 = (float*)htake((size_t)B_ * M_ * KN_ * E_ * 4);
  float* xx2 = (float*)htake((size_t)B_ * M_ * KN_ * L_ * 4);
  float* xx3 = (float*)htake((size_t)B_ * M_ * KN_ * E_ * 4);
  float* tmat = (float*)htake((size_t)B_ * M_ * KN_ * E_ * 4);
  short* tmat_bf = (short*)htake((size_t)B_ * M_ * KN_ * E_ * 2);
  float* mpart = (float*)htake((size_t)1024 * NSPLIT_ * 4);
  float* spart = (float*)htake((size_t)1024 * NSPLIT_ * 4);
  float* cent = (float*)htake((size_t)B_ * M_ * 4);

  dim3 blk(256);
  embed_init_k<<<BL_, blk, 0, stream>>>(masked, embed, pos, xsa, xsa_bf, xsaT_bf);

  for (int d = 0; d < D_; d++) {
    const float* Wt_d = Wt + (long)d * E_ * E_;
    const float* Wc_d = Wc + (long)d * E_ * E_;
    const float* Wq_d = Wq + (long)d * KE_ * E_;
    const float* Wd_d = Wd + (long)d * KE_ * KE_;
    const float* Wo_d = Wo + (long)d * KE_ * E_;
    wcvt_k<<<5376, blk, 0, stream>>>(Wt_d, Wc_d, Wq_d, Wd_d, Wo_d, wt_bf, wc_bf,
                                     wq_bf, wd_bf, wtT_bf, wcT_bf, woT_bf);

    // t1 = relu(roll(+1) @ Wt)
    mg128_k<true, false, false, true, 1><<<dim3(2, 16, 1), blk, 0, stream>>>(
        xsa_bf, wtT_bf, t1_bf, 1.f, E_, E_, E_, E_, 1, 0, 0, 0, 0, 0, 0);
    // xsad = t1 @ Wc
    mg128_k<false, false, false, false, 0><<<dim3(2, 16, 1), blk, 0, stream>>>(
        t1_bf, wcT_bf, xsad, 1.f, E_, E_, E_, E_, 1, 0, 0, 0, 0, 0, 0);
    // t2 = relu(roll(-1) @ Wc^T)
    mg128_k<true, false, false, true, -1><<<dim3(2, 16, 1), blk, 0, stream>>>(
        xsa_bf, wc_bf, t1_bf, 1.f, E_, E_, E_, E_, 1, 0, 0, 0, 0, 0, 0);
    // xsad += t2 @ Wt^T
    mg128_k<false, true, false, false, 0><<<dim3(2, 16, 1), blk, 0, stream>>>(
        t1_bf, wt_bf, xsad, 1.f, E_, E_, E_, E_, 1, 0, 0, 0, 0, 0, 0);
    // q = xsa @ Wq^T
    mg128_k<false, false, false, true, 0><<<dim3(16, 16, 1), blk, 0, stream>>>(
        xsa_bf, wq_bf, q_bf, 1.f, E_, E_, E_, KE_, 1, 0, 0, 0, 0, 0, 0);
    // scores = q @ xsa^T / 16
    mg128_k<false, false, true, false, 0><<<dim3(4, 4, B_ * K_), blk, 0, stream>>>(
        q_bf, xsa_bf, sc, 0.0625f, E_, KE_, E_, L_, K_, (long)L_ * KE_, E_,
        (long)L_ * E_, 0, (long)K_ * L_ * L_, (long)L_ * L_);
    softmax_bf_k<<<B_ * K_ * L_, blk, 0, stream>>>(sc);
    // yik = P @ xsa
    mg128_k<false, false, false, true, 0><<<dim3(2, 4, B_ * K_), blk, 0, stream>>>(
        (const short*)sc, xsaT_bf, y_bf, 1.f, L_, L_ * 2, L_, KE_, K_,
        (long)K_ * L_ * L_ * 2, (long)L_ * L_ * 2, (long)E_ * L_, 0,
        (long)L_ * KE_, E_);
    // xid = relu(yik @ Wd^T)
    mg128_k<true, false, false, true, 0><<<dim3(16, 16, 1), blk, 0, stream>>>(
        y_bf, wd_bf, q_bf, 1.f, KE_, KE_, KE_, KE_, 1, 0, 0, 0, 0, 0, 0);
    // xsad += xid @ Wo
    mg128_k<false, true, false, false, 0><<<dim3(2, 16, 1), blk, 0, stream>>>(
        q_bf, woT_bf, xsad, 1.f, KE_, KE_, KE_, E_, 1, 0, 0, 0, 0, 0, 0);

    update_norm_k<<<BL_, blk, 0, stream>>>(xsa, xsad, xsa_bf, xsaT_bf);
  }

  // ---- loss head ----
  gather_k<<<B_ * M_, blk, 0, stream>>>(xsa, mask, lptok);
  gemm_k<true, true><<<dim3(16, 4, 1), blk, 0, stream>>>(
      lptok, Wkc, xx1, bkc, B_ * M_, KN_ * E_, E_, E_, E_, KN_ * E_, 0, 0, 0);
  gemm_k<true, false><<<dim3(8, 4, B_), blk, 0, stream>>>(
      xx1, xsa, xx2, nullptr, M_ * KN_, L_, E_, E_, E_, L_,
      (long)M_ * KN_ * E_, (long)L_ * E_, (long)M_ * KN_ * L_);
  gemm_k<false, false><<<dim3(4, 4, B_), blk, 0, stream>>>(
      xx2, xsa, xx3, nullptr, M_ * KN_, E_, L_, L_, E_, E_,
      (long)M_ * KN_ * L_, (long)L_ * E_, (long)M_ * KN_ * E_);
  gemm_k<false, false><<<dim3(4, 4, B_), blk, 0, stream>>>(
      xx3, Wem, tmat, nullptr, M_ * KN_, E_, E_, E_, E_, E_,
      (long)M_ * KN_ * E_, 0, (long)M_ * KN_ * E_);
  cvt_k<<<8000, blk, 0, stream>>>(embed, embed_bf, G_ * E_ / 4);
  cvt_k<<<256, blk, 0, stream>>>(tmat, tmat_bf, B_ * M_ * KN_ * E_ / 4);
  lse2_k<<<dim3(NSPLIT_, 16), blk, 0, stream>>>(tmat_bf, embed_bf, mpart, spart);
  cent_k<<<B_ * M_, blk, 0, stream>>>(tmat, embed, mask, unmasked, mpart, spart, cent);
  loss_k<<<1, blk, 0, stream>>>(cent, summer, out);
}

// Round 4
// 1120.711 us; speedup vs baseline: 3.8487x; 1.1761x over previous
//
#include <hip/hip_runtime.h>
#include <math.h>
#include <stdint.h>

#define G_ 32000
#define E_ 256
#define K_ 8
#define D_ 6
#define B_ 4
#define L_ 512
#define M_ 64
#define KN_ 4
#define STEP_ 0.05f
#define BL_ (B_ * L_)   // 2048
#define KE_ (K_ * E_)   // 2048
#define NSPLIT_ 50
#define GCH_ 10         // 64-col chunks per split: 50*10*64 = 32000

typedef __attribute__((ext_vector_type(8))) short short8;
typedef __attribute__((ext_vector_type(4))) float f32x4;
typedef __attribute__((ext_vector_type(4))) short short4v;

__device__ __forceinline__ short f2bf(float f) {
  unsigned u = __builtin_bit_cast(unsigned, f);
  unsigned r = (u + 0x7fffu + ((u >> 16) & 1u)) >> 16;
  return (short)r;
}

__device__ __forceinline__ void gload16(const void* g, void* l) {
  __builtin_amdgcn_global_load_lds(
      reinterpret_cast<const __attribute__((address_space(1))) void*>(
          reinterpret_cast<uintptr_t>(g)),
      reinterpret_cast<__attribute__((address_space(3))) void*>(
          reinterpret_cast<uintptr_t>(l)),
      16, 0, 0);
}

// ---------------- reduction helpers ----------------
__device__ __forceinline__ float wsum(float v) {
#pragma unroll
  for (int o = 32; o > 0; o >>= 1) v += __shfl_xor(v, o, 64);
  return v;
}
__device__ __forceinline__ float block_sum(float v, float* sm) {
  v = wsum(v);
  int wid = threadIdx.x >> 6, lane = threadIdx.x & 63;
  if (lane == 0) sm[wid] = v;
  __syncthreads();
  float r = sm[0] + sm[1] + sm[2] + sm[3];
  __syncthreads();
  return r;
}

// ---------------- 128x128 MFMA GEMM (m97 structure) ----------------
template <bool RELU, bool ACC, bool SCL, bool OBF, int ROLL>
__global__ __launch_bounds__(256) void mg128_k(
    const short* __restrict__ Ag, const short* __restrict__ Bg,
    void* __restrict__ Cg, float scale, int Kd, int lda, int ldb, int ldc,
    int batch2, long sA1, long sA2, long sB1, long sB2, long sC1, long sC2) {
  __shared__ short As[128 * 64];
  __shared__ short Bs[128 * 64];
  int bz = blockIdx.z;
  int b1 = bz / batch2, b2 = bz - b1 * batch2;
  const short* A = Ag + b1 * sA1 + b2 * sA2;
  const short* B = Bg + b1 * sB1 + b2 * sB2;
  int m0 = blockIdx.y * 128, n0 = blockIdx.x * 128;
  int t = threadIdx.x, w = t >> 6, l = t & 63;
  int l16 = l & 15, qd = l >> 4, hi8 = qd * 8;
  int wr_ = w >> 1, wc_ = w & 1;
  int sr = l >> 3;
  int scol = ((l & 7) * 8) ^ (sr << 3);
  f32x4 acc[4][4];
#pragma unroll
  for (int i = 0; i < 4; i++)
#pragma unroll
    for (int j = 0; j < 4; j++) acc[i][j] = {0.f, 0.f, 0.f, 0.f};

  for (int k0 = 0; k0 < Kd; k0 += 64) {
    __syncthreads();
#pragma unroll
    for (int c = 0; c < 4; c++) {
      int sub = w * 4 + c;
      int r = sub * 8 + sr;
      int gr = m0 + r;
      if (ROLL != 0) {
        int bb = gr >> 9, pp = gr & (L_ - 1);
        gr = (bb << 9) | ((pp - ROLL + L_) & (L_ - 1));
      }
      gload16(A + (long)gr * lda + k0 + scol, &As[sub * 512]);
    }
#pragma unroll
    for (int c = 0; c < 4; c++) {
      int sub = w * 4 + c;
      int r = sub * 8 + sr;
      gload16(B + (long)(n0 + r) * ldb + k0 + scol, &Bs[sub * 512]);
    }
    __syncthreads();
#pragma unroll
    for (int ks = 0; ks < 2; ks++) {
      short8 af[4], bf[4];
#pragma unroll
      for (int rf = 0; rf < 4; rf++) {
        int row = wr_ * 64 + rf * 16 + l16;
        af[rf] = *(const short8*)&As[(row * 64 + ks * 32 + hi8) ^ ((row & 7) << 3)];
      }
#pragma unroll
      for (int cf = 0; cf < 4; cf++) {
        int row = wc_ * 64 + cf * 16 + l16;
        bf[cf] = *(const short8*)&Bs[(row * 64 + ks * 32 + hi8) ^ ((row & 7) << 3)];
      }
#pragma unroll
      for (int rf = 0; rf < 4; rf++)
#pragma unroll
        for (int cf = 0; cf < 4; cf++)
          acc[rf][cf] = __builtin_amdgcn_mfma_f32_16x16x32_bf16(
              af[rf], bf[cf], acc[rf][cf], 0, 0, 0);
    }
  }
  long cb = b1 * sC1 + b2 * sC2;
#pragma unroll
  for (int rf = 0; rf < 4; rf++) {
#pragma unroll
    for (int cf = 0; cf < 4; cf++) {
      int col = n0 + wc_ * 64 + cf * 16 + l16;
#pragma unroll
      for (int j = 0; j < 4; j++) {
        int row = m0 + wr_ * 64 + rf * 16 + qd * 4 + j;
        float v = acc[rf][cf][j];
        if (SCL) v *= scale;
        if (RELU) v = fmaxf(v, 0.f);
        long idx = (long)row * ldc + col;
        if (OBF) {
          ((short*)Cg + cb)[idx] = f2bf(v);
        } else {
          float* C = (float*)Cg + cb;
          if (ACC) v += C[idx];
          C[idx] = v;
        }
      }
    }
  }
}

// ---------------- z-batched transition pair ----------------
// z=0: T[:,0:256]   = relu(roll(+1,xsa) @ Wt)    (B = Wt^T form)
// z=1: T[:,256:512] = relu(roll(-1,xsa) @ Wc^T)  (B = Wc form)
__global__ __launch_bounds__(256) void tpair_k(
    const short* __restrict__ xsa_bf, const short* __restrict__ wtT,
    const short* __restrict__ wcb, short* __restrict__ T) {
  __shared__ short As[128 * 64];
  __shared__ short Bs[128 * 64];
  int z = blockIdx.z;
  const short* Bb = z ? wcb : wtT;
  int rollv = z ? -1 : 1;
  int m0 = blockIdx.y * 128, n0 = blockIdx.x * 128;
  int t = threadIdx.x, w = t >> 6, l = t & 63;
  int l16 = l & 15, qd = l >> 4, hi8 = qd * 8;
  int wr_ = w >> 1, wc_ = w & 1;
  int sr = l >> 3;
  int scol = ((l & 7) * 8) ^ (sr << 3);
  f32x4 acc[4][4];
#pragma unroll
  for (int i = 0; i < 4; i++)
#pragma unroll
    for (int j = 0; j < 4; j++) acc[i][j] = {0.f, 0.f, 0.f, 0.f};
  for (int k0 = 0; k0 < E_; k0 += 64) {
    __syncthreads();
#pragma unroll
    for (int c = 0; c < 4; c++) {
      int sub = w * 4 + c;
      int r = sub * 8 + sr;
      int gr = m0 + r;
      int bb = gr >> 9, pp = gr & (L_ - 1);
      gr = (bb << 9) | ((pp - rollv + L_) & (L_ - 1));
      gload16(xsa_bf + (long)gr * E_ + k0 + scol, &As[sub * 512]);
    }
#pragma unroll
    for (int c = 0; c < 4; c++) {
      int sub = w * 4 + c;
      int r = sub * 8 + sr;
      gload16(Bb + (long)(n0 + r) * E_ + k0 + scol, &Bs[sub * 512]);
    }
    __syncthreads();
#pragma unroll
    for (int ks = 0; ks < 2; ks++) {
      short8 af[4], bf[4];
#pragma unroll
      for (int rf = 0; rf < 4; rf++) {
        int row = wr_ * 64 + rf * 16 + l16;
        af[rf] = *(const short8*)&As[(row * 64 + ks * 32 + hi8) ^ ((row & 7) << 3)];
      }
#pragma unroll
      for (int cf = 0; cf < 4; cf++) {
        int row = wc_ * 64 + cf * 16 + l16;
        bf[cf] = *(const short8*)&Bs[(row * 64 + ks * 32 + hi8) ^ ((row & 7) << 3)];
      }
#pragma unroll
      for (int rf = 0; rf < 4; rf++)
#pragma unroll
        for (int cf = 0; cf < 4; cf++)
          acc[rf][cf] = __builtin_amdgcn_mfma_f32_16x16x32_bf16(
              af[rf], bf[cf], acc[rf][cf], 0, 0, 0);
    }
  }
#pragma unroll
  for (int rf = 0; rf < 4; rf++) {
#pragma unroll
    for (int cf = 0; cf < 4; cf++) {
      int col = n0 + wc_ * 64 + cf * 16 + l16;
#pragma unroll
      for (int j = 0; j < 4; j++) {
        int row = m0 + wr_ * 64 + rf * 16 + qd * 4 + j;
        T[(long)row * 512 + z * 256 + col] = f2bf(fmaxf(acc[rf][cf][j], 0.f));
      }
    }
  }
}

// ---------------- fused flash attention ----------------
// grid (L/64, K_, B_). Per block: 64 q-rows of head k, full L kv sweep.
// y[b, l, k, :] = softmax(q . xsa^T / 16) @ xsa
__global__ __launch_bounds__(256) void flash_k(
    const short* __restrict__ q_bf, const short* __restrict__ xsa_bf,
    const short* __restrict__ xsaT_bf, short* __restrict__ y_bf) {
  __shared__ short Qs[64 * 256];
  __shared__ short Ks[64 * 256];
  __shared__ short Vt[256 * 64];
  __shared__ short Ps[64 * 64];
  __shared__ float ml[64], ll[64], al[64];
  int q0 = blockIdx.x * 64, hk = blockIdx.y, b = blockIdx.z;
  int t = threadIdx.x, w = t >> 6, l = t & 63;
  int l16 = l & 15, qd = l >> 4, hi8 = qd * 8;
  const float scale = 0.0625f;
  // stage Q (64 x 256)
  {
    int r2 = l >> 5, colL = (l & 31) * 8;
#pragma unroll
    for (int c = 0; c < 8; c++) {
      int rl = c * 8 + w * 2 + r2;
      int scol = colL ^ ((rl & 7) << 3);
      gload16(q_bf + (long)(b * L_ + q0 + rl) * KE_ + hk * 256 + scol,
              &Qs[(c * 8 + w * 2) * 256]);
    }
  }
  if (t < 64) { ml[t] = -1e30f; ll[t] = 0.f; }
  f32x4 acc_o[4][4];
#pragma unroll
  for (int i = 0; i < 4; i++)
#pragma unroll
    for (int j = 0; j < 4; j++) acc_o[i][j] = {0.f, 0.f, 0.f, 0.f};
  __syncthreads();

  for (int kv = 0; kv < L_ / 64; kv++) {
    int kv0 = kv * 64;
    // stage K (64 x 256) and Vt (256 x 64)
    {
      int r2 = l >> 5, colL = (l & 31) * 8;
#pragma unroll
      for (int c = 0; c < 8; c++) {
        int rl = c * 8 + w * 2 + r2;
        int scol = colL ^ ((rl & 7) << 3);
        gload16(xsa_bf + (long)(b * L_ + kv0 + rl) * E_ + scol,
                &Ks[(c * 8 + w * 2) * 256]);
      }
      int sr = l >> 3, colV = (l & 7) * 8;
      int scolV = colV ^ (sr << 3);
#pragma unroll
      for (int c = 0; c < 8; c++) {
        int sub = c * 4 + w;
        int rl = sub * 8 + sr;
        gload16(xsaT_bf + (long)(b * E_ + rl) * L_ + kv0 + scolV, &Vt[sub * 512]);
      }
    }
    __syncthreads();
    // S band: rows w*16..w*16+15, cols 0..63, K=256
    f32x4 s4[4];
#pragma unroll
    for (int cf = 0; cf < 4; cf++) s4[cf] = {0.f, 0.f, 0.f, 0.f};
#pragma unroll
    for (int ks = 0; ks < 8; ks++) {
      int ra = w * 16 + l16;
      short8 a = *(const short8*)&Qs[ra * 256 + ((ks * 32 + hi8) ^ ((ra & 7) << 3))];
#pragma unroll
      for (int cf = 0; cf < 4; cf++) {
        int rb = cf * 16 + l16;
        short8 bb = *(const short8*)&Ks[rb * 256 + ((ks * 32 + hi8) ^ ((rb & 7) << 3))];
        s4[cf] = __builtin_amdgcn_mfma_f32_16x16x32_bf16(a, bb, s4[cf], 0, 0, 0);
      }
    }
    // online softmax stats (rows of band owned by this wave)
#pragma unroll
    for (int j = 0; j < 4; j++) {
      int rq = w * 16 + qd * 4 + j;
      float v0 = s4[0][j] * scale, v1 = s4[1][j] * scale;
      float v2 = s4[2][j] * scale, v3 = s4[3][j] * scale;
      float rmax = fmaxf(fmaxf(v0, v1), fmaxf(v2, v3));
#pragma unroll
      for (int mk = 1; mk <= 8; mk <<= 1) rmax = fmaxf(rmax, __shfl_xor(rmax, mk, 64));
      float mo = ml[rq];
      float mn = fmaxf(mo, rmax);
      float p0 = __expf(v0 - mn), p1 = __expf(v1 - mn);
      float p2 = __expf(v2 - mn), p3 = __expf(v3 - mn);
      float ps = p0 + p1 + p2 + p3;
#pragma unroll
      for (int mk = 1; mk <= 8; mk <<= 1) ps += __shfl_xor(ps, mk, 64);
      float alpha = __expf(mo - mn);
      if (l16 == 0) {
        ml[rq] = mn;
        ll[rq] = ll[rq] * alpha + ps;
        al[rq] = alpha;
      }
      int sw = (rq & 7) << 3;
      Ps[rq * 64 + ((0 + l16) ^ sw)] = f2bf(p0);
      Ps[rq * 64 + ((16 + l16) ^ sw)] = f2bf(p1);
      Ps[rq * 64 + ((32 + l16) ^ sw)] = f2bf(p2);
      Ps[rq * 64 + ((48 + l16) ^ sw)] = f2bf(p3);
    }
    __syncthreads();
    // rescale O, then PV (wave owns cols w*64..w*64+63, all 64 rows)
#pragma unroll
    for (int rf = 0; rf < 4; rf++)
#pragma unroll
      for (int j = 0; j < 4; j++) {
        float a_ = al[rf * 16 + qd * 4 + j];
#pragma unroll
        for (int cf = 0; cf < 4; cf++) acc_o[rf][cf][j] *= a_;
      }
#pragma unroll
    for (int ks2 = 0; ks2 < 2; ks2++) {
#pragma unroll
      for (int rf = 0; rf < 4; rf++) {
        int rp = rf * 16 + l16;
        short8 a = *(const short8*)&Ps[rp * 64 + ((ks2 * 32 + hi8) ^ ((rp & 7) << 3))];
#pragma unroll
        for (int cf = 0; cf < 4; cf++) {
          int rv = w * 64 + cf * 16 + l16;
          short8 bb = *(const short8*)&Vt[rv * 64 + ((ks2 * 32 + hi8) ^ ((rv & 7) << 3))];
          acc_o[rf][cf] = __builtin_amdgcn_mfma_f32_16x16x32_bf16(a, bb, acc_o[rf][cf], 0, 0, 0);
        }
      }
    }
    __syncthreads();
  }
  // epilogue: y = O / l
#pragma unroll
  for (int rf = 0; rf < 4; rf++)
#pragma unroll
    for (int j = 0; j < 4; j++) {
      int row = rf * 16 + qd * 4 + j;
      float inv = 1.0f / ll[row];
#pragma unroll
      for (int cf = 0; cf < 4; cf++) {
        y_bf[(long)(b * L_ + q0 + row) * KE_ + hk * 256 + w * 64 + cf * 16 + l16] =
            f2bf(acc_o[rf][cf][j] * inv);
      }
    }
}

// ---------------- fused logits (MFMA, A-in-registers) + online LSE ----------
__global__ __launch_bounds__(256) void lse2_k(
    const short* __restrict__ tmat_bf, const short* __restrict__ embed_bf,
    float* __restrict__ mpart, float* __restrict__ spart) {
  __shared__ short Bs[64 * 256];
  int split = blockIdx.x, rb = blockIdx.y;
  int t = threadIdx.x, w = t >> 6, l = t & 63;
  int l16 = l & 15, qd = l >> 4, hi8 = qd * 8;
  short8 areg[8];
  {
    const short* ar = tmat_bf + (long)(rb * 64 + w * 16 + l16) * E_;
#pragma unroll
    for (int ks = 0; ks < 8; ks++) areg[ks] = *(const short8*)(ar + ks * 32 + hi8);
  }
  float m[4], s[4];
#pragma unroll
  for (int j = 0; j < 4; j++) { m[j] = -1e30f; s[j] = 0.f; }
  long gbase = (long)split * (GCH_ * 64);
  for (int ch = 0; ch < GCH_; ch++) {
    long g0 = gbase + ch * 64;
    __syncthreads();
#pragma unroll
    for (int j = 0; j < 8; j++) {
      int sub = w * 8 + j;
      int r = sub * 2 + (l >> 5);
      int col = ((l & 31) * 8) ^ ((r & 7) << 3);
      gload16(embed_bf + (g0 + r) * E_ + col, &Bs[sub * 512]);
    }
    __syncthreads();
    f32x4 acc[4];
#pragma unroll
    for (int cf = 0; cf < 4; cf++) acc[cf] = {0.f, 0.f, 0.f, 0.f};
#pragma unroll
    for (int ks = 0; ks < 8; ks++) {
#pragma unroll
      for (int cf = 0; cf < 4; cf++) {
        int row = cf * 16 + l16;
        short8 b = *(const short8*)&Bs[(row * 256 + ks * 32 + hi8) ^ ((row & 7) << 3)];
        acc[cf] = __builtin_amdgcn_mfma_f32_16x16x32_bf16(areg[ks], b, acc[cf], 0, 0, 0);
      }
    }
#pragma unroll
    for (int j = 0; j < 4; j++) {
      float vm = fmaxf(fmaxf(acc[0][j], acc[1][j]), fmaxf(acc[2][j], acc[3][j]));
      float mn = fmaxf(m[j], vm);
      s[j] = s[j] * __expf(m[j] - mn) + __expf(acc[0][j] - mn) +
             __expf(acc[1][j] - mn) + __expf(acc[2][j] - mn) +
             __expf(acc[3][j] - mn);
      m[j] = mn;
    }
  }
#pragma unroll
  for (int j = 0; j < 4; j++) {
#pragma unroll
    for (int mask = 1; mask <= 8; mask <<= 1) {
      float mo = __shfl_xor(m[j], mask, 64);
      float so = __shfl_xor(s[j], mask, 64);
      float mn = fmaxf(m[j], mo);
      s[j] = s[j] * __expf(m[j] - mn) + so * __expf(mo - mn);
      m[j] = mn;
    }
    if (l16 == 0) {
      int row = rb * 64 + w * 16 + qd * 4 + j;
      mpart[(long)row * NSPLIT_ + split] = m[j];
      spart[(long)row * NSPLIT_ + split] = s[j];
    }
  }
}

// ---------------- fused per-layer weight conversion ----------------
__device__ __forceinline__ void cvt_blk(const float* __restrict__ src,
                                        short* __restrict__ dst, int blk, int t) {
  int i = blk * 256 + t;
  float4 v = ((const float4*)src)[i];
  short4v o = {f2bf(v.x), f2bf(v.y), f2bf(v.z), f2bf(v.w)};
  ((short4v*)dst)[i] = o;
}
__device__ __forceinline__ void trans_blk(const float* __restrict__ src,
                                          short* __restrict__ dst, int bx, int by,
                                          int C, int ldd, float (*tile)[33], int t) {
  int c0 = bx * 32, r0 = by * 32;
  int tx = t & 31, ty = t >> 5;
#pragma unroll
  for (int k = 0; k < 4; k++)
    tile[ty + k * 8][tx] = src[(long)(r0 + ty + k * 8) * C + c0 + tx];
  __syncthreads();
#pragma unroll
  for (int k = 0; k < 4; k++)
    dst[(long)(c0 + ty + k * 8) * ldd + r0 + tx] = f2bf(tile[tx][ty + k * 8]);
}
// grid: 4096 wd | 512 wq | 64 wc | 64 wtT | 512 woT | 64 wcat_tr | 64 wcat_cp
__global__ __launch_bounds__(256) void wcvt_k(
    const float* __restrict__ Wt_d, const float* __restrict__ Wc_d,
    const float* __restrict__ Wq_d, const float* __restrict__ Wd_d,
    const float* __restrict__ Wo_d, short* wcb, short* wq, short* wd,
    short* wtT, short* woT, short* wcat) {
  __shared__ float tile[32][33];
  int blk = blockIdx.x, t = threadIdx.x;
  if (blk < 4096) { cvt_blk(Wd_d, wd, blk, t); return; }
  blk -= 4096;
  if (blk < 512) { cvt_blk(Wq_d, wq, blk, t); return; }
  blk -= 512;
  if (blk < 64) { cvt_blk(Wc_d, wcb, blk, t); return; }
  blk -= 64;
  if (blk < 64) { trans_blk(Wt_d, wtT, blk & 7, blk >> 3, E_, E_, tile, t); return; }
  blk -= 64;
  if (blk < 512) { trans_blk(Wo_d, woT, blk & 7, blk >> 3, E_, KE_, tile, t); return; }
  blk -= 512;
  if (blk < 64) { trans_blk(Wc_d, wcat, blk & 7, blk >> 3, E_, 512, tile, t); return; }
  blk -= 64;
  {  // wcat[n][256+k] = Wt[n][k]
    int i = blk * 256 + t;
    int n = i >> 6, kc = (i & 63) * 4;
    float4 v = *(const float4*)(Wt_d + (long)n * E_ + kc);
    short4v o = {f2bf(v.x), f2bf(v.y), f2bf(v.z), f2bf(v.w)};
    *(short4v*)(wcat + (long)n * 512 + 256 + kc) = o;
  }
}

// ---------------- small fused kernels ----------------
__global__ __launch_bounds__(256) void cvt_k(const float* __restrict__ src,
                                             short* __restrict__ dst, int n4) {
  int i = blockIdx.x * 256 + threadIdx.x;
  if (i < n4) {
    float4 v = ((const float4*)src)[i];
    short4v o = {f2bf(v.x), f2bf(v.y), f2bf(v.z), f2bf(v.w)};
    ((short4v*)dst)[i] = o;
  }
}

__global__ __launch_bounds__(256) void embed_init_k(
    const int* __restrict__ masked, const float* __restrict__ embed,
    const float* __restrict__ pos, float* __restrict__ xsa,
    short* __restrict__ xsa_bf, short* __restrict__ xsaT_bf) {
  int bl = blockIdx.x;
  int b = bl / L_, ll = bl % L_;
  int t = threadIdx.x;
  __shared__ float sm[4];
  int tok = masked[bl];
  float v = embed[(long)tok * E_ + t] + pos[(long)ll * E_ + t];
  float s1 = block_sum(v, sm);
  float s2 = block_sum(v * v, sm);
  float mean = s1 * (1.0f / E_);
  float var = (s2 - s1 * mean) * (1.0f / (E_ - 1));
  float xn = v / (1.0f + sqrtf(fmaxf(var, 0.f)));
  xsa[(long)bl * E_ + t] = xn;
  short h = f2bf(xn);
  xsa_bf[(long)bl * E_ + t] = h;
  xsaT_bf[((long)b * E_ + t) * L_ + ll] = h;
}

__global__ __launch_bounds__(256) void update_norm_k(
    float* __restrict__ xsa, const float* __restrict__ xsad,
    short* __restrict__ xsa_bf, short* __restrict__ xsaT_bf) {
  long r = blockIdx.x;
  int b = (int)(r / L_), ll = (int)(r % L_);
  int t = threadIdx.x;
  __shared__ float sm[4];
  float vd = xsad[r * E_ + t];
  float s1 = block_sum(vd, sm);
  float s2 = block_sum(vd * vd, sm);
  float mean = s1 * (1.0f / E_);
  float var = (s2 - s1 * mean) * (1.0f / (E_ - 1));
  float vdn = vd / (1.0f + sqrtf(fmaxf(var, 0.f)));
  float u = xsa[r * E_ + t] + STEP_ * vdn;
  s1 = block_sum(u, sm);
  s2 = block_sum(u * u, sm);
  mean = s1 * (1.0f / E_);
  var = (s2 - s1 * mean) * (1.0f / (E_ - 1));
  float xn = u / (1.0f + sqrtf(fmaxf(var, 0.f)));
  xsa[r * E_ + t] = xn;
  short h = f2bf(xn);
  xsa_bf[r * E_ + t] = h;
  xsaT_bf[((long)b * E_ + t) * L_ + ll] = h;
}

__global__ __launch_bounds__(256) void gather_k(const float* __restrict__ xsa,
                                                const int* __restrict__ mask,
                                                float* __restrict__ lptok) {
  int bm = blockIdx.x;
  int b = bm >> 6;
  int t = threadIdx.x;
  int p = mask[bm];
  lptok[(long)bm * E_ + t] = xsa[((long)b * L_ + p) * E_ + t];
}

// ---------------- fp32 tiled GEMM (small head matmuls) ----------------
template <bool TRB, bool BIAS>
__global__ __launch_bounds__(256) void gemm_k(
    const float* __restrict__ Ag, const float* __restrict__ Bg,
    float* __restrict__ Cg, const float* __restrict__ bias, int M, int N,
    int Kd, int lda, int ldb, int ldc, long sA1, long sB1, long sC1) {
  constexpr int BM = 64, BN = 64, BK = 16, TM = 4, TN = 4;
  int b1 = blockIdx.z;
  const float* A = Ag + b1 * sA1;
  const float* Bp = Bg + b1 * sB1;
  float* C = Cg + b1 * sC1;
  int m0 = blockIdx.y * BM, n0 = blockIdx.x * BN;
  __shared__ float As[BK][BM + 4];
  __shared__ float Bs[BK][BN + 4];
  int t = threadIdx.x;
  int tx = t % (BN / TN), ty = t / (BN / TN);
  float acc[TM][TN];
#pragma unroll
  for (int i = 0; i < TM; i++)
#pragma unroll
    for (int j = 0; j < TN; j++) acc[i][j] = 0.f;
  for (int k0 = 0; k0 < Kd; k0 += BK) {
    __syncthreads();
    {
      int r = t / (BK / 4), kc = (t % (BK / 4)) * 4;
      float4 v = *(const float4*)(A + (long)(m0 + r) * lda + k0 + kc);
      As[kc + 0][r] = v.x;
      As[kc + 1][r] = v.y;
      As[kc + 2][r] = v.z;
      As[kc + 3][r] = v.w;
    }
    if (!TRB) {
      int r = t / (BN / 4), nc = (t % (BN / 4)) * 4;
      *(float4*)(&Bs[r][nc]) = *(const float4*)(Bp + (long)(k0 + r) * ldb + n0 + nc);
    } else {
      int n = t / (BK / 4), kc = (t % (BK / 4)) * 4;
      float4 v = *(const float4*)(Bp + (long)(n0 + n) * ldb + k0 + kc);
      Bs[kc + 0][n] = v.x;
      Bs[kc + 1][n] = v.y;
      Bs[kc + 2][n] = v.z;
      Bs[kc + 3][n] = v.w;
    }
    __syncthreads();
#pragma unroll
    for (int kk = 0; kk < BK; kk++) {
      float a[TM], b[TN];
#pragma unroll
      for (int i = 0; i < TM; i++) a[i] = As[kk][ty * TM + i];
#pragma unroll
      for (int j = 0; j < TN; j++) b[j] = Bs[kk][tx * TN + j];
#pragma unroll
      for (int i = 0; i < TM; i++)
#pragma unroll
        for (int j = 0; j < TN; j++) acc[i][j] = fmaf(a[i], b[j], acc[i][j]);
    }
  }
#pragma unroll
  for (int i = 0; i < TM; i++) {
    long row = m0 + ty * TM + i;
    float* cp = C + row * (long)ldc + n0 + tx * TN;
#pragma unroll
    for (int j = 0; j < TN; j++) {
      float v = acc[i][j];
      if (BIAS) v += bias[n0 + tx * TN + j];
      cp[j] = v;
    }
  }
}

__global__ __launch_bounds__(256) void cent_k(
    const float* __restrict__ tmat, const float* __restrict__ embed,
    const int* __restrict__ mask, const int* __restrict__ unmasked,
    const float* __restrict__ mpart, const float* __restrict__ spart,
    float* __restrict__ cent) {
  int bm = blockIdx.x;
  int b = bm >> 6, m = bm & 63;
  int t = threadIdx.x;
  __shared__ float sm[4];
  __shared__ float tlv[KN_];
  int pos = mask[bm];
  int tgt = unmasked[b * L_ + pos];
  float ev = embed[(long)tgt * E_ + t];
  for (int kn = 0; kn < KN_; kn++) {
    long grow = (long)b * (M_ * KN_) + m * KN_ + kn;
    float dot = block_sum(tmat[grow * E_ + t] * ev, sm);
    if (t == 0) {
      float M = -1e30f, S = 0.f;
      for (int i = 0; i < NSPLIT_; i++) {
        float m2 = mpart[grow * NSPLIT_ + i], s2 = spart[grow * NSPLIT_ + i];
        float MM = fmaxf(M, m2);
        S = S * __expf(M - MM) + s2 * __expf(m2 - MM);
        M = MM;
      }
      tlv[kn] = dot - (M + __logf(S));
    }
  }
  __syncthreads();
  if (t == 0) {
    float mx = fmaxf(fmaxf(tlv[0], tlv[1]), fmaxf(tlv[2], tlv[3]));
    float s = __expf(tlv[0] - mx) + __expf(tlv[1] - mx) + __expf(tlv[2] - mx) +
              __expf(tlv[3] - mx);
    cent[bm] = __logf(s) + mx - 1.3862943611198906f;
  }
}

__global__ __launch_bounds__(256) void loss_k(const float* __restrict__ cent,
                                              const float* __restrict__ summer,
                                              float* __restrict__ out) {
  int t = threadIdx.x;
  int b = t >> 6, m = t & 63;
  float c = cent[b * 64 + m], su = summer[b * 64 + m];
  float num = wsum(c * su);
  float den = wsum(su);
  if (m == 0) out[b] = -num / fmaxf(den, 1.0f);
}

// ---------------- launcher ----------------
extern "C" void kernel_launch(void* const* d_in, const int* in_sizes, int n_in,
                              void* d_out, int out_size, void* d_ws,
                              size_t ws_size, hipStream_t stream) {
  (void)in_sizes; (void)n_in; (void)out_size; (void)ws_size;
  const int* masked = (const int*)d_in[0];
  const int* unmasked = (const int*)d_in[1];
  const int* mask = (const int*)d_in[2];
  const float* summer = (const float*)d_in[3];
  const float* embed = (const float*)d_in[4];
  const float* pos = (const float*)d_in[5];
  const float* Wt = (const float*)d_in[6];
  const float* Wc = (const float*)d_in[7];
  const float* Wq = (const float*)d_in[8];
  const float* Wd = (const float*)d_in[9];
  const float* Wo = (const float*)d_in[10];
  const float* Wkc = (const float*)d_in[11];
  const float* bkc = (const float*)d_in[12];
  const float* Wem = (const float*)d_in[13];
  float* out = (float*)d_out;

  char* p = (char*)d_ws;
  auto take = [&](size_t bytes) {
    char* r = p;
    p += (bytes + 255) & ~(size_t)255;
    return r;
  };
  float* xsa = (float*)take((size_t)BL_ * E_ * 4);
  float* xsad = (float*)take((size_t)BL_ * E_ * 4);
  short* xsa_bf = (short*)take((size_t)BL_ * E_ * 2);
  short* xsaT_bf = (short*)take((size_t)BL_ * E_ * 2);
  short* t_buf = (short*)take((size_t)BL_ * 512 * 2);
  short* q_bf = (short*)take((size_t)BL_ * KE_ * 2);  // reused as xid
  short* y_bf = (short*)take((size_t)BL_ * KE_ * 2);
  short* wc_bf = (short*)take((size_t)E_ * E_ * 2);
  short* wtT_bf = (short*)take((size_t)E_ * E_ * 2);
  short* wq_bf = (short*)take((size_t)KE_ * E_ * 2);
  short* wd_bf = (short*)take((size_t)KE_ * KE_ * 2);
  short* woT_bf = (short*)take((size_t)KE_ * E_ * 2);
  short* wcat_bf = (short*)take((size_t)E_ * 512 * 2);
  short* embed_bf = (short*)take((size_t)G_ * E_ * 2);
  float* lptok = (float*)take((size_t)B_ * M_ * E_ * 4);
  float* xx1 = (float*)take((size_t)B_ * M_ * KN_ * E_ * 4);
  float* xx2 = (float*)take((size_t)B_ * M_ * KN_ * L_ * 4);
  float* xx3 = (float*)take((size_t)B_ * M_ * KN_ * E_ * 4);
  float* tmat = (float*)take((size_t)B_ * M_ * KN_ * E_ * 4);
  short* tmat_bf = (short*)take((size_t)B_ * M_ * KN_ * E_ * 2);
  float* mpart = (float*)take((size_t)1024 * NSPLIT_ * 4);
  float* spart = (float*)take((size_t)1024 * NSPLIT_ * 4);
  float* cent = (float*)take((size_t)B_ * M_ * 4);

  dim3 blk(256);
  embed_init_k<<<BL_, blk, 0, stream>>>(masked, embed, pos, xsa, xsa_bf, xsaT_bf);

  for (int d = 0; d < D_; d++) {
    const float* Wt_d = Wt + (long)d * E_ * E_;
    const float* Wc_d = Wc + (long)d * E_ * E_;
    const float* Wq_d = Wq + (long)d * KE_ * E_;
    const float* Wd_d = Wd + (long)d * KE_ * KE_;
    const float* Wo_d = Wo + (long)d * KE_ * E_;
    wcvt_k<<<5376, blk, 0, stream>>>(Wt_d, Wc_d, Wq_d, Wd_d, Wo_d, wc_bf, wq_bf,
                                     wd_bf, wtT_bf, woT_bf, wcat_bf);

    // T = [relu(roll+1 @ Wt) | relu(roll-1 @ Wc^T)]
    tpair_k<<<dim3(2, 16, 2), blk, 0, stream>>>(xsa_bf, wtT_bf, wc_bf, t_buf);
    // xsad = T @ [Wc ; Wt^T]
    mg128_k<false, false, false, false, 0><<<dim3(2, 16, 1), blk, 0, stream>>>(
        t_buf, wcat_bf, xsad, 1.f, 512, 512, 512, E_, 1, 0, 0, 0, 0, 0, 0);
    // q = xsa @ Wq^T
    mg128_k<false, false, false, true, 0><<<dim3(16, 16, 1), blk, 0, stream>>>(
        xsa_bf, wq_bf, q_bf, 1.f, E_, E_, E_, KE_, 1, 0, 0, 0, 0, 0, 0);
    // fused attention: y = softmax(q.xsa^T/16) @ xsa
    flash_k<<<dim3(L_ / 64, K_, B_), blk, 0, stream>>>(q_bf, xsa_bf, xsaT_bf, y_bf);
    // xid = relu(y @ Wd^T)
    mg128_k<true, false, false, true, 0><<<dim3(16, 16, 1), blk, 0, stream>>>(
        y_bf, wd_bf, q_bf, 1.f, KE_, KE_, KE_, KE_, 1, 0, 0, 0, 0, 0, 0);
    // xsad += xid @ Wo
    mg128_k<false, true, false, false, 0><<<dim3(2, 16, 1), blk, 0, stream>>>(
        q_bf, woT_bf, xsad, 1.f, KE_, KE_, KE_, E_, 1, 0, 0, 0, 0, 0, 0);

    update_norm_k<<<BL_, blk, 0, stream>>>(xsa, xsad, xsa_bf, xsaT_bf);
  }

  // ---- loss head ----
  gather_k<<<B_ * M_, blk, 0, stream>>>(xsa, mask, lptok);
  gemm_k<true, true><<<dim3(16, 4, 1), blk, 0, stream>>>(
      lptok, Wkc, xx1, bkc, B_ * M_, KN_ * E_, E_, E_, E_, KN_ * E_, 0, 0, 0);
  gemm_k<true, false><<<dim3(8, 4, B_), blk, 0, stream>>>(
      xx1, xsa, xx2, nullptr, M_ * KN_, L_, E_, E_, E_, L_,
      (long)M_ * KN_ * E_, (long)L_ * E_, (long)M_ * KN_ * L_);
  gemm_k<false, false><<<dim3(4, 4, B_), blk, 0, stream>>>(
      xx2, xsa, xx3, nullptr, M_ * KN_, E_, L_, L_, E_, E_,
      (long)M_ * KN_ * L_, (long)L_ * E_, (long)M_ * KN_ * E_);
  gemm_k<false, false><<<dim3(4, 4, B_), blk, 0, stream>>>(
      xx3, Wem, tmat, nullptr, M_ * KN_, E_, E_, E_, E_, E_,
      (long)M_ * KN_ * E_, 0, (long)M_ * KN_ * E_);
  cvt_k<<<8000, blk, 0, stream>>>(embed, embed_bf, G_ * E_ / 4);
  cvt_k<<<256, blk, 0, stream>>>(tmat, tmat_bf, B_ * M_ * KN_ * E_ / 4);
  lse2_k<<<dim3(NSPLIT_, 16), blk, 0, stream>>>(tmat_bf, embed_bf, mpart, spart);
  cent_k<<<B_ * M_, blk, 0, stream>>>(tmat, embed, mask, unmasked, mpart, spart, cent);
  loss_k<<<1, blk, 0, stream>>>(cent, summer, out);
}